// Round 12
// baseline (349.737 us; speedup 1.0000x reference)
//
#include <hip/hip_runtime.h>
#include <hip/hip_bf16.h>
#include <hip/hip_fp16.h>

#define NN 102400      // B*T*NODES
#define DD 64
#define EE 1638400
#define L1C 96
#define L2C 64
#define TT 32
#define NODESC 400
#define BB 8
#define SS 3200        // B*NODES
#define G4 256         // 4*D

#define NBUK 400       // coarse buckets (node >> 8), NN = 400*256 exactly
#define BCAP 5120      // slots per bucket (mean 4096, sd 64 -> +16 sigma)
#define PCHUNK 2048    // 800 blocks x 512 thr
#define NPART (EE / PCHUNK)   // 800
#define PTHR 512
#define EPT (PCHUNK / PTHR)   // 4 edges per thread

// ---------------- workspace layout (floats) ----------------
#define OFF_ENT  ((size_t)0)          // NBUK*BCAP int2 = 4,096,000 floats
#define OFF_A1   ((size_t)4096000)    // NN*64 fp16 a1 rows
#define OFF_ENT2 ((size_t)26214400)   // csr staging; then xnd bf16; then h2 bf16
#define OFF_H2   ((size_t)26214400)   // NN*64 bf16 (overwrites dead xnd)
#define OFF_G2   ((size_t)32768000)   // NN*64 fp16
#define OFF_GCUR ((size_t)39321600)   // 400 cursors padded x16 ints = 6400
#define OFF_DIS  ((size_t)39328000)   // NN -> ends 39,430,400
#define OFF_RNG  ((size_t)39430400)   // NN int2 -> ends 39,635,200
#define OFF_ST   ((size_t)39840000)   // 256 -> ends 39,840,256

typedef __attribute__((ext_vector_type(8))) _Float16 f16x8;  // 8 f16 in 4 VGPRs
typedef __attribute__((ext_vector_type(4))) float f32x4;

__device__ __forceinline__ void fma4(float4& a, float s, const float4& w) {
    a.x = fmaf(s, w.x, a.x); a.y = fmaf(s, w.y, a.y);
    a.z = fmaf(s, w.z, a.z); a.w = fmaf(s, w.w, a.w);
}
__device__ __forceinline__ float rcp_f(float x) { return __builtin_amdgcn_rcpf(x); }
__device__ __forceinline__ float sigm_f(float x) {
    x = fminf(fmaxf(x, -30.f), 30.f);
    return rcp_f(1.f + __expf(-x));
}
__device__ __forceinline__ float tanh_f(float x) {
    x = fminf(fmaxf(x, -15.f), 15.f);
    float e = __expf(2.f * x);
    return (e - 1.f) * rcp_f(e + 1.f);
}
__device__ __forceinline__ unsigned short f32_bf16_rtne(float f) {
    unsigned int u = __float_as_uint(f);
    unsigned int r = u + 0x7fffu + ((u >> 16) & 1u);
    return (unsigned short)(r >> 16);
}
__device__ __forceinline__ float bf16_f32(unsigned short h) {
    return __uint_as_float(((unsigned int)h) << 16);
}
// bf16 x4 pack/unpack (gather tables)
__device__ __forceinline__ float4 unp4(uint2 p) {
    float4 v;
    v.x = __uint_as_float(p.x << 16);
    v.y = __uint_as_float(p.x & 0xffff0000u);
    v.z = __uint_as_float(p.y << 16);
    v.w = __uint_as_float(p.y & 0xffff0000u);
    return v;
}
__device__ __forceinline__ uint2 pk4(float4 v) {
    unsigned int u0 = ((unsigned int)f32_bf16_rtne(v.y) << 16) | f32_bf16_rtne(v.x);
    unsigned int u1 = ((unsigned int)f32_bf16_rtne(v.w) << 16) | f32_bf16_rtne(v.z);
    return make_uint2(u0, u1);
}
// fp16 x4 pack/unpack (GEMM intermediates)
__device__ __forceinline__ uint2 pkh4(float4 v) {
    __half2 h0 = __floats2half2_rn(v.x, v.y);
    __half2 h1 = __floats2half2_rn(v.z, v.w);
    uint2 r;
    r.x = *(unsigned int*)&h0;
    r.y = *(unsigned int*)&h1;
    return r;
}
__device__ __forceinline__ float4 uph4(uint2 p) {
    __half2 h0 = *(__half2*)&p.x;
    __half2 h1 = *(__half2*)&p.y;
    float2 f0 = __half22float2(h0), f1 = __half22float2(h1);
    return make_float4(f0.x, f0.y, f1.x, f1.y);
}

// ---------------- init: zero bucket cursors + stats ----------------
__global__ void init_zero(int* gcur, float* st) {
    int idx = blockIdx.x * 256 + threadIdx.x;
    if (idx < NBUK * 16) gcur[idx] = 0;
    if (blockIdx.x == 0 && threadIdx.x < 128) st[threadIdx.x] = 0.f;
}

// ---------------- normalization stats ----------------
__global__ __launch_bounds__(256) void col_sums(const float* __restrict__ x, float* __restrict__ st) {
    int c = threadIdx.x & 63;
    size_t i = (size_t)blockIdx.x * 256 + threadIdx.x;
    size_t stride = (size_t)gridDim.x * 256;
    float s = 0.f, q = 0.f;
    for (size_t e = i; e < (size_t)NN * 64; e += stride) {
        float v = x[e]; s += v; q = fmaf(v, v, q);
    }
    __shared__ float ls[128];
    if (threadIdx.x < 128) ls[threadIdx.x] = 0.f;
    __syncthreads();
    atomicAdd(&ls[c], s); atomicAdd(&ls[64 + c], q);
    __syncthreads();
    if (threadIdx.x < 128) atomicAdd(&st[threadIdx.x], ls[threadIdx.x]);
}

__global__ void finalize_stats(float* st) {
    int c = threadIdx.x;
    if (c < 64) {
        float s = st[c], q = st[64 + c];
        float mean = s / (float)NN;
        float var = (q - s * s / (float)NN) / (float)(NN - 1);
        st[128 + c] = mean;
        st[192 + c] = rsqrtf(fmaxf(var, 1e-20f));
    }
}

// ---------------- xnd = bf16( dis[n] * normalize(x[n]) ) ----------------
__global__ __launch_bounds__(256) void xnd_kernel(const float* __restrict__ x, const float* __restrict__ st,
                                                  const float* __restrict__ dis, uint2* __restrict__ xnd) {
    size_t i = (size_t)blockIdx.x * 256 + threadIdx.x;   // float4 index
    int n = (int)(i >> 4), q = (int)(i & 15);
    float4 v = ((const float4*)x)[i];
    float4 mean4 = ((const float4*)(st + 128))[q];
    float4 istd4 = ((const float4*)(st + 192))[q];
    float dn = dis[n];
    v.x = (v.x - mean4.x) * istd4.x * dn;
    v.y = (v.y - mean4.y) * istd4.y * dn;
    v.z = (v.z - mean4.z) * istd4.z * dn;
    v.w = (v.w - mean4.w) * istd4.w * dn;
    xnd[i] = pk4(v);
}

// ---------------- pass 1: coarse bucket partition, LDS-staged coalesced writes ----------------
__global__ __launch_bounds__(PTHR) void part_kernel(const int* __restrict__ ei, const float* __restrict__ ea,
                                                    int* __restrict__ gcur, int2* __restrict__ ent2) {
    __shared__ int lhist[NBUK];        // counts, then reused as scatter cursors
    __shared__ int lofs[NBUK];         // block-local exclusive offsets
    __shared__ int lbase[NBUK];        // global within-bucket base (from gcur)
    __shared__ int scn[PTHR];          // scan workspace
    __shared__ int2 stage[PCHUNK];     // 16 KB bucket-sorted staging
    __shared__ int  gdst[PCHUNK];      // 8 KB absolute destinations (-1 = drop)
    const int tid = threadIdx.x;
    const int e0 = blockIdx.x * PCHUNK;
    for (int i = tid; i < NBUK; i += PTHR) lhist[i] = 0;
    __syncthreads();
    int   dv[EPT]; int sv[EPT]; float wvv[EPT];
    #pragma unroll
    for (int i = 0; i < EPT; ++i) {
        int e = e0 + i * PTHR + tid;
        dv[i]  = ei[EE + e];
        sv[i]  = ei[e];
        wvv[i] = fabsf(ea[2 * (size_t)e]);
        atomicAdd(&lhist[dv[i] >> 8], 1);
    }
    __syncthreads();
    // exclusive prefix over bucket counts (Hillis-Steele over PTHR lanes)
    scn[tid] = (tid < NBUK) ? lhist[tid] : 0;
    __syncthreads();
    for (int d = 1; d < PTHR; d <<= 1) {
        int t = (tid >= d) ? scn[tid - d] : 0;
        __syncthreads();
        scn[tid] += t;
        __syncthreads();
    }
    if (tid < NBUK) {
        lofs[tid]  = scn[tid] - lhist[tid];                  // exclusive
        lbase[tid] = atomicAdd(&gcur[tid * 16], lhist[tid]); // reserve global run
        lhist[tid] = 0;                                      // reuse as cursor
    }
    __syncthreads();
    // scatter into bucket-sorted LDS staging + precompute global destination
    #pragma unroll
    for (int i = 0; i < EPT; ++i) {
        int d = dv[i];
        int b = d >> 8;
        int li = atomicAdd(&lhist[b], 1);
        int pos = lofs[b] + li;
        stage[pos] = make_int2(sv[i] | ((d & 255) << 24), __float_as_int(wvv[i]));
        int gp_ = lbase[b] + li;
        gdst[pos] = (gp_ < BCAP) ? (b * BCAP + gp_) : -1;
    }
    __syncthreads();
    // write out: consecutive lanes cover consecutive addresses within segments
    for (int i = tid; i < PCHUNK; i += PTHR) {
        int g = gdst[i];
        if (g >= 0) ent2[g] = stage[i];
    }
}

// ---------------- pass 2: per-bucket counting sort in LDS + rng + dis ----------------
// v2: sort into a 40 KB LDS buffer, then write ent fully coalesced (the old
// random 8B scatter writes were the same pattern part_kernel lost on).
__global__ __launch_bounds__(256) void bucket_csr(const int2* __restrict__ ent2, const int* __restrict__ gcur,
                                                  int2* __restrict__ ent, int2* __restrict__ rng,
                                                  float* __restrict__ dis) {
    __shared__ int nhist[256];
    __shared__ int scn[256];
    __shared__ float wsum[256];
    __shared__ int pcur[256];
    __shared__ int2 sorted[BCAP];   // 40 KB
    const int tid = threadIdx.x;
    const int b = blockIdx.x;
    const int base = b * BCAP;
    int cnt = gcur[b * 16];
    if (cnt > BCAP) cnt = BCAP;
    nhist[tid] = 0;
    wsum[tid] = 0.f;
    __syncthreads();
    for (int e = tid; e < cnt; e += 256) {
        int2 en = ent2[base + e];
        int dl = ((unsigned)en.x) >> 24;
        atomicAdd(&nhist[dl], 1);
        atomicAdd(&wsum[dl], __int_as_float(en.y));
    }
    __syncthreads();
    int c = nhist[tid];
    scn[tid] = c;
    __syncthreads();
    for (int d = 1; d < 256; d <<= 1) {
        int t = (tid >= d) ? scn[tid - d] : 0;
        __syncthreads();
        scn[tid] += t;
        __syncthreads();
    }
    int ps = scn[tid] - c;                       // exclusive prefix within bucket
    rng[b * 256 + tid] = make_int2(base + ps, base + ps + c);
    dis[b * 256 + tid] = rsqrtf(1.f + wsum[tid]); // self-loop weight 1 folded in
    pcur[tid] = ps;
    __syncthreads();
    for (int e = tid; e < cnt; e += 256) {
        int2 en = ent2[base + e];
        int dl = ((unsigned)en.x) >> 24;
        int local = atomicAdd(&pcur[dl], 1);
        sorted[local] = make_int2(en.x & 0xFFFFFF, en.y);
    }
    __syncthreads();
    // coalesced write-out
    for (int e = tid; e < cnt; e += 256)
        ent[base + e] = sorted[e];
}

// ---------------- fused MFMA GEMM 1+2: h2 = bf16(dis*(relu(a1@W1 + b1)@W2)) ----------------
#define G1_LD 72
#define G2_LD 104
__global__ __launch_bounds__(256) void fused_gemm12(
    const unsigned short* __restrict__ A, const float* __restrict__ W1,
    const float* __restrict__ b1v, const float* __restrict__ W2,
    const float* __restrict__ dscale, unsigned short* __restrict__ h2out)
{
    __shared__ __align__(16) _Float16 As[64 * G1_LD];    // a1 rows f16 (9.2 KB)
    __shared__ __align__(16) _Float16 G1s[64 * G2_LD];   // relu(g1+b1) f16 (13.3 KB)
    __shared__ float ds[64];
    const int tid  = threadIdx.x;
    const int lane = tid & 63;
    const int wv   = tid >> 6;          // wave 0..3
    const int n15  = lane & 15;
    const int quad = lane >> 4;
    const size_t row0 = (size_t)blockIdx.x * 64;

    if (tid < 64) ds[tid] = dscale[row0 + tid];

    // ---- W1 frags: ctiles {wv, wv+4 if wv<2} covering 0..5; hi + lo*2048 f16 ----
    const int nt1 = (wv < 2) ? 2 : 1;
    f16x8 w1h[2][2], w1l[2][2];
    float b1c[2] = {0.f, 0.f};
    #pragma unroll
    for (int t = 0; t < 2; ++t) {
        if (t < nt1) {
            const int col = (wv + 4 * t) * 16 + n15;
            b1c[t] = b1v[col];
            #pragma unroll
            for (int kc = 0; kc < 2; ++kc) {
                #pragma unroll
                for (int j = 0; j < 8; ++j) {
                    float w = W1[(size_t)(kc * 32 + quad * 8 + j) * 96 + col];
                    _Float16 h = (_Float16)w;
                    w1h[t][kc][j] = h;
                    w1l[t][kc][j] = (_Float16)((w - (float)h) * 2048.f);
                }
            }
        }
    }
    // ---- W2 frags: ctile wv, col = wv*16+n15, 3 k-chunks ----
    f16x8 w2h[3], w2l[3];
    {
        const int col = wv * 16 + n15;
        #pragma unroll
        for (int kc = 0; kc < 3; ++kc) {
            #pragma unroll
            for (int j = 0; j < 8; ++j) {
                float w = W2[(size_t)(kc * 32 + quad * 8 + j) * 64 + col];
                _Float16 h = (_Float16)w;
                w2h[kc][j] = h;
                w2l[kc][j] = (_Float16)((w - (float)h) * 2048.f);
            }
        }
    }

    // ---- stage a1 rows (already fp16): coalesced uint2 copy ----
    for (int i = tid; i < 64 * 16; i += 256) {
        int r = i >> 4, c4 = i & 15;
        uint2 p = *(const uint2*)(A + (row0 + r) * 64 + c4 * 4);
        *(uint2*)(As + r * G1_LD + c4 * 4) = p;
    }
    __syncthreads();

    // ---- phase B: g1 = a1 @ W1, relu(g1+b1) -> G1s f16 ----
    {
        f32x4 acc1[2][4], accl1[2][4];
        #pragma unroll
        for (int t = 0; t < 2; ++t)
            #pragma unroll
            for (int rt = 0; rt < 4; ++rt) {
                acc1[t][rt]  = (f32x4){0.f, 0.f, 0.f, 0.f};
                accl1[t][rt] = (f32x4){0.f, 0.f, 0.f, 0.f};
            }
        #pragma unroll
        for (int kc = 0; kc < 2; ++kc) {
            #pragma unroll
            for (int rt = 0; rt < 4; ++rt) {
                f16x8 a = *(const f16x8*)(As + (rt * 16 + n15) * G1_LD + kc * 32 + quad * 8);
                acc1[0][rt]  = __builtin_amdgcn_mfma_f32_16x16x32_f16(a, w1h[0][kc], acc1[0][rt],  0, 0, 0);
                accl1[0][rt] = __builtin_amdgcn_mfma_f32_16x16x32_f16(a, w1l[0][kc], accl1[0][rt], 0, 0, 0);
                if (nt1 == 2) {
                    acc1[1][rt]  = __builtin_amdgcn_mfma_f32_16x16x32_f16(a, w1h[1][kc], acc1[1][rt],  0, 0, 0);
                    accl1[1][rt] = __builtin_amdgcn_mfma_f32_16x16x32_f16(a, w1l[1][kc], accl1[1][rt], 0, 0, 0);
                }
            }
        }
        #pragma unroll
        for (int t = 0; t < 2; ++t) {
            if (t < nt1) {
                const int col = (wv + 4 * t) * 16 + n15;
                #pragma unroll
                for (int rt = 0; rt < 4; ++rt) {
                    f32x4 c = acc1[t][rt] + accl1[t][rt] * (1.f / 2048.f);
                    #pragma unroll
                    for (int r = 0; r < 4; ++r) {
                        int row = rt * 16 + quad * 4 + r;
                        G1s[row * G2_LD + col] = (_Float16)fmaxf(c[r] + b1c[t], 0.f);
                    }
                }
            }
        }
    }
    __syncthreads();

    // ---- phase C: h2 = bf16(dis * (relu_g1 @ W2)) ----
    {
        f32x4 acc[4], accl[4];
        #pragma unroll
        for (int rt = 0; rt < 4; ++rt) {
            acc[rt]  = (f32x4){0.f, 0.f, 0.f, 0.f};
            accl[rt] = (f32x4){0.f, 0.f, 0.f, 0.f};
        }
        #pragma unroll
        for (int kc = 0; kc < 3; ++kc) {
            #pragma unroll
            for (int rt = 0; rt < 4; ++rt) {
                f16x8 a = *(const f16x8*)(G1s + (rt * 16 + n15) * G2_LD + kc * 32 + quad * 8);
                acc[rt]  = __builtin_amdgcn_mfma_f32_16x16x32_f16(a, w2h[kc], acc[rt],  0, 0, 0);
                accl[rt] = __builtin_amdgcn_mfma_f32_16x16x32_f16(a, w2l[kc], accl[rt], 0, 0, 0);
            }
        }
        const int col = wv * 16 + n15;
        #pragma unroll
        for (int rt = 0; rt < 4; ++rt) {
            f32x4 c = acc[rt] + accl[rt] * (1.f / 2048.f);
            #pragma unroll
            for (int r = 0; r < 4; ++r) {
                int row = rt * 16 + quad * 4 + r;
                float v = c[r] * ds[row];
                h2out[(row0 + row) * 64 + col] = f32_bf16_rtne(v);
            }
        }
    }
}

// ---------------- GCN aggregation: gather over packed CSR (rng int2 ranges) ----------------
template<int C4>
__global__ __launch_bounds__(256) void gcn_gather(const uint2* __restrict__ h, const int2* __restrict__ rng,
                                                  const int2* __restrict__ ent, const float* __restrict__ dis,
                                                  unsigned short* __restrict__ g) {
    unsigned int idx = blockIdx.x * 256 + threadIdx.x;
    unsigned int n = idx / C4, q = idx % C4;
    float4 acc = unp4(h[(size_t)n * C4 + q]);
    int2 r = rng[n];
    int e = r.x;
    for (; e + 8 <= r.y; e += 8) {
        int2 en0 = ent[e],     en1 = ent[e + 1], en2 = ent[e + 2], en3 = ent[e + 3];
        int2 en4 = ent[e + 4], en5 = ent[e + 5], en6 = ent[e + 6], en7 = ent[e + 7];
        uint2 v0 = h[(size_t)en0.x * C4 + q];
        uint2 v1 = h[(size_t)en1.x * C4 + q];
        uint2 v2 = h[(size_t)en2.x * C4 + q];
        uint2 v3 = h[(size_t)en3.x * C4 + q];
        uint2 v4 = h[(size_t)en4.x * C4 + q];
        uint2 v5 = h[(size_t)en5.x * C4 + q];
        uint2 v6 = h[(size_t)en6.x * C4 + q];
        uint2 v7 = h[(size_t)en7.x * C4 + q];
        fma4(acc, __int_as_float(en0.y), unp4(v0));
        fma4(acc, __int_as_float(en1.y), unp4(v1));
        fma4(acc, __int_as_float(en2.y), unp4(v2));
        fma4(acc, __int_as_float(en3.y), unp4(v3));
        fma4(acc, __int_as_float(en4.y), unp4(v4));
        fma4(acc, __int_as_float(en5.y), unp4(v5));
        fma4(acc, __int_as_float(en6.y), unp4(v6));
        fma4(acc, __int_as_float(en7.y), unp4(v7));
    }
    for (; e + 4 <= r.y; e += 4) {
        int2 en0 = ent[e], en1 = ent[e + 1], en2 = ent[e + 2], en3 = ent[e + 3];
        uint2 v0 = h[(size_t)en0.x * C4 + q];
        uint2 v1 = h[(size_t)en1.x * C4 + q];
        uint2 v2 = h[(size_t)en2.x * C4 + q];
        uint2 v3 = h[(size_t)en3.x * C4 + q];
        fma4(acc, __int_as_float(en0.y), unp4(v0));
        fma4(acc, __int_as_float(en1.y), unp4(v1));
        fma4(acc, __int_as_float(en2.y), unp4(v2));
        fma4(acc, __int_as_float(en3.y), unp4(v3));
    }
    for (; e < r.y; ++e) {
        int2 en = ent[e];
        uint2 v = h[(size_t)en.x * C4 + q];
        fma4(acc, __int_as_float(en.y), unp4(v));
    }
    float dn = dis[n];
    acc.x *= dn; acc.y *= dn; acc.z *= dn; acc.w *= dn;
    *(uint2*)(g + (size_t)n * (C4 * 4) + q * 4) = pkh4(acc);
}

// ---------------- fused LSTM + FC head: recurrence, then fc1/fc2/softmax in-block ----------------
// v3 recurrence (8 waves, 2 gate-tiles/wave — best measured ~42us) + fused
// head epilogue: h stays in registers -> gp scratch -> fc1(relu)+fc2+softmax,
// probs written directly to out. Drops head_kernel launch + hlast round-trip.
#define XP_LD 72   // xpack seq-row stride (halves): 4*(n15+quad) bank spread
#define HP_LD2 72  // h plane row stride (halves)
#define GP_LD 258  // gp row stride (floats): store banks 8q+2r+n15 = 2/bank floor

__global__ __launch_bounds__(512, 1) void lstm_kernel(
    const __half* __restrict__ g2, const float* __restrict__ cb2,
    const float* __restrict__ whh, const float* __restrict__ wih,
    const float* __restrict__ bih, const float* __restrict__ bhh,
    const float* __restrict__ fc1w, const float* __restrict__ fc1b,
    const float* __restrict__ fc2w, const float* __restrict__ fc2b,
    float* __restrict__ out)
{
    __shared__ __align__(16) _Float16 xpack[32 * 16 * XP_LD];  // 73.7 KB
    __shared__ __align__(16) _Float16 hhi[16 * HP_LD2];        // 2.25 KB
    __shared__ __align__(16) _Float16 hlo[16 * HP_LD2];        // 2.25 KB
    __shared__ __align__(16) float gp[16 * GP_LD];             // 16.1 KB (also head scratch)
    const int tid  = threadIdx.x;       // 0..511
    const int lane = tid & 63;
    const int wv   = tid >> 6;          // wave 0..7
    const int n15  = lane & 15;         // A: seq m / B: gate-in-tile n
    const int quad = lane >> 4;         // k sub-block
    const int ja   = lane;              // activation hidden unit 0..63

    // ---- loop-invariant B-frags for 2 gate tiles: gate = (wv+8*tl)*16+n15 ----
    f16x8 whh_h[2][2], whh_l[2][2], wih_h[2][2], wih_l[2][2];  // [tile][kc]
    #pragma unroll
    for (int tl = 0; tl < 2; ++tl) {
        const int gate = (wv + 8 * tl) * 16 + n15;
        const float* wp = whh + (size_t)gate * 64 + quad * 8;
        const float* xp = wih + (size_t)gate * 64 + quad * 8;
        #pragma unroll
        for (int kc = 0; kc < 2; ++kc) {
            #pragma unroll
            for (int j = 0; j < 8; ++j) {
                float w = wp[kc * 32 + j];
                _Float16 h = (_Float16)w;
                whh_h[tl][kc][j] = h;
                whh_l[tl][kc][j] = (_Float16)((w - (float)h) * 2048.f);
                float v = xp[kc * 32 + j];
                _Float16 g = (_Float16)v;
                wih_h[tl][kc][j] = g;
                wih_l[tl][kc][j] = (_Float16)((v - (float)g) * 2048.f);
            }
        }
    }

    // ---- activation-phase gate biases (b_ih + b_hh), f32 (depend on ja only) ----
    const float bi_i = bih[ja]        + bhh[ja];
    const float bi_f = bih[64 + ja]   + bhh[64 + ja];
    const float bi_g = bih[128 + ja]  + bhh[128 + ja];
    const float bi_o = bih[192 + ja]  + bhh[192 + ja];

    // ---- prologue: stage xr = relu(g2 + conv2_b) into xpack, fully coalesced ----
    {
        const int s0 = blockIdx.x * 16;          // 400 % 16 == 0: block never straddles b_
        const int b_ = s0 / NODESC;
        const int node0 = s0 - b_ * NODESC;
        const int r  = (tid >> 4) & 15;          // seq row (fixed per thread)
        const int c4 = tid & 15;                 // 4-half group within row
        const int t0 = tid >> 8;                 // 0..1; t = t0 + 2*i
        float4 bias4 = *(const float4*)(cb2 + c4 * 4);
        _Float16* dst = xpack + r * XP_LD + c4 * 4;
        const __half* src = g2 + ((size_t)(b_ * TT + t0) * NODESC + node0 + r) * 64 + c4 * 4;
        #pragma unroll
        for (int i = 0; i < 16; ++i) {
            uint2 p = *(const uint2*)(src + (size_t)i * 2 * NODESC * 64);
            float4 v = uph4(p);
            v.x = fmaxf(v.x + bias4.x, 0.f);
            v.y = fmaxf(v.y + bias4.y, 0.f);
            v.z = fmaxf(v.z + bias4.z, 0.f);
            v.w = fmaxf(v.w + bias4.w, 0.f);
            *(uint2*)(dst + (size_t)(t0 + i * 2) * (16 * XP_LD)) = pkh4(v);
        }
    }

    // ---- init h = 0 ----
    for (int i = tid; i < 16 * HP_LD2; i += 512) { hhi[i] = (_Float16)0.f; hlo[i] = (_Float16)0.f; }
    float cA_reg = 0.f, hA = 0.f;   // state for (qa = wv, ja)
    float cB_reg = 0.f, hB = 0.f;   // state for (qa = wv+8, ja)
    __syncthreads();

    const int xbase = n15 * XP_LD + quad * 8;    // halves, 16B-aligned
    const int hbase = n15 * HP_LD2 + quad * 8;

    for (int t = 0; t < TT; ++t) {
        // ---- dot phase: 6 A-frag reads shared by 2 tiles, 20 MFMAs, 6 chains ----
        f32x4 cmA  = {0.f,0.f,0.f,0.f}, clA0 = {0.f,0.f,0.f,0.f}, clA1 = {0.f,0.f,0.f,0.f};
        f32x4 cmB  = {0.f,0.f,0.f,0.f}, clB0 = {0.f,0.f,0.f,0.f}, clB1 = {0.f,0.f,0.f,0.f};
        const _Float16* xrow = xpack + (size_t)t * (16 * XP_LD);
        {
            f16x8 ax0 = *(const f16x8*)(xrow + xbase);
            f16x8 ah0 = *(const f16x8*)(hhi + hbase);
            f16x8 al0 = *(const f16x8*)(hlo + hbase);
            f16x8 ax1 = *(const f16x8*)(xrow + xbase + 32);
            f16x8 ah1 = *(const f16x8*)(hhi + hbase + 32);
            f16x8 al1 = *(const f16x8*)(hlo + hbase + 32);
            cmA  = __builtin_amdgcn_mfma_f32_16x16x32_f16(ax0, wih_h[0][0], cmA,  0, 0, 0);
            cmB  = __builtin_amdgcn_mfma_f32_16x16x32_f16(ax0, wih_h[1][0], cmB,  0, 0, 0);
            clA0 = __builtin_amdgcn_mfma_f32_16x16x32_f16(ax0, wih_l[0][0], clA0, 0, 0, 0);
            clB0 = __builtin_amdgcn_mfma_f32_16x16x32_f16(ax0, wih_l[1][0], clB0, 0, 0, 0);
            clA1 = __builtin_amdgcn_mfma_f32_16x16x32_f16(ax1, wih_l[0][1], clA1, 0, 0, 0);
            clB1 = __builtin_amdgcn_mfma_f32_16x16x32_f16(ax1, wih_l[1][1], clB1, 0, 0, 0);
            cmA  = __builtin_amdgcn_mfma_f32_16x16x32_f16(ah0, whh_h[0][0], cmA,  0, 0, 0);
            cmB  = __builtin_amdgcn_mfma_f32_16x16x32_f16(ah0, whh_h[1][0], cmB,  0, 0, 0);
            clA0 = __builtin_amdgcn_mfma_f32_16x16x32_f16(al0, whh_h[0][0], clA0, 0, 0, 0);
            clB0 = __builtin_amdgcn_mfma_f32_16x16x32_f16(al0, whh_h[1][0], clB0, 0, 0, 0);
            clA1 = __builtin_amdgcn_mfma_f32_16x16x32_f16(al1, whh_h[0][1], clA1, 0, 0, 0);
            clB1 = __builtin_amdgcn_mfma_f32_16x16x32_f16(al1, whh_h[1][1], clB1, 0, 0, 0);
            cmA  = __builtin_amdgcn_mfma_f32_16x16x32_f16(ax1, wih_h[0][1], cmA,  0, 0, 0);
            cmB  = __builtin_amdgcn_mfma_f32_16x16x32_f16(ax1, wih_h[1][1], cmB,  0, 0, 0);
            clA0 = __builtin_amdgcn_mfma_f32_16x16x32_f16(ah0, whh_l[0][0], clA0, 0, 0, 0);
            clB0 = __builtin_amdgcn_mfma_f32_16x16x32_f16(ah0, whh_l[1][0], clB0, 0, 0, 0);
            clA1 = __builtin_amdgcn_mfma_f32_16x16x32_f16(ah1, whh_l[0][1], clA1, 0, 0, 0);
            clB1 = __builtin_amdgcn_mfma_f32_16x16x32_f16(ah1, whh_l[1][1], clB1, 0, 0, 0);
            cmA  = __builtin_amdgcn_mfma_f32_16x16x32_f16(ah1, whh_h[0][1], cmA,  0, 0, 0);
            cmB  = __builtin_amdgcn_mfma_f32_16x16x32_f16(ah1, whh_h[1][1], cmB,  0, 0, 0);
        }
        f32x4 cA = cmA + (clA0 + clA1) * (1.f / 2048.f);
        f32x4 cB = cmB + (clB0 + clB1) * (1.f / 2048.f);
        // C: lane holds seqs m = quad*4+r; columns wv*16+n15 and (wv+8)*16+n15
        #pragma unroll
        for (int r = 0; r < 4; ++r) {
            gp[(quad * 4 + r) * GP_LD + wv * 16 + n15]       = cA[r];
            gp[(quad * 4 + r) * GP_LD + (wv + 8) * 16 + n15] = cB[r];
        }
        __syncthreads();

        // ---- activation phase: thread handles (wv, ja) and (wv+8, ja) ----
        {
            const int qa = wv;
            float gi = gp[qa * GP_LD + ja]        + bi_i;
            float gf = gp[qa * GP_LD + 64 + ja]   + bi_f;
            float gg = gp[qa * GP_LD + 128 + ja]  + bi_g;
            float go = gp[qa * GP_LD + 192 + ja]  + bi_o;
            cA_reg = sigm_f(gf) * cA_reg + sigm_f(gi) * tanh_f(gg);
            hA = sigm_f(go) * tanh_f(cA_reg);
            _Float16 hh = (_Float16)hA;
            hhi[qa * HP_LD2 + ja] = hh;
            hlo[qa * HP_LD2 + ja] = (_Float16)((hA - (float)hh) * 2048.f);
        }
        {
            const int qa = wv + 8;
            float gi = gp[qa * GP_LD + ja]        + bi_i;
            float gf = gp[qa * GP_LD + 64 + ja]   + bi_f;
            float gg = gp[qa * GP_LD + 128 + ja]  + bi_g;
            float go = gp[qa * GP_LD + 192 + ja]  + bi_o;
            cB_reg = sigm_f(gf) * cB_reg + sigm_f(gi) * tanh_f(gg);
            hB = sigm_f(go) * tanh_f(cB_reg);
            _Float16 hh = (_Float16)hB;
            hhi[qa * HP_LD2 + ja] = hh;
            hlo[qa * HP_LD2 + ja] = (_Float16)((hB - (float)hh) * 2048.f);
        }
        __syncthreads();
    }

    // ---- fused FC head + softmax (gp reused: hrow[16][64] | a1[16][128] | lg[16][3]) ----
    gp[wv * 64 + ja]       = hA;
    gp[(wv + 8) * 64 + ja] = hB;
    __syncthreads();
    #pragma unroll
    for (int k = 0; k < 4; ++k) {
        int task = tid + k * 512;          // 2048 tasks: seq s x fc1-out o
        int s = task >> 7, o = task & 127;
        const float4* wr = (const float4*)(fc1w + (size_t)o * 64);
        const float4* hq = (const float4*)(gp + s * 64);
        float4 acc = make_float4(0.f, 0.f, 0.f, 0.f);
        #pragma unroll
        for (int kk = 0; kk < 16; ++kk) {
            float4 w4 = wr[kk]; float4 h4 = hq[kk];
            acc.x = fmaf(w4.x, h4.x, acc.x); acc.y = fmaf(w4.y, h4.y, acc.y);
            acc.z = fmaf(w4.z, h4.z, acc.z); acc.w = fmaf(w4.w, h4.w, acc.w);
        }
        gp[1024 + s * 128 + o] = fmaxf((acc.x + acc.y) + (acc.z + acc.w) + fc1b[o], 0.f);
    }
    __syncthreads();
    if (tid < 48) {
        int s = tid / 3, c = tid - s * 3;
        const float4* wr = (const float4*)(fc2w + (size_t)c * 128);
        const float4* aq = (const float4*)(gp + 1024 + s * 128);
        float4 acc = make_float4(0.f, 0.f, 0.f, 0.f);
        #pragma unroll
        for (int kk = 0; kk < 32; ++kk) {
            float4 w4 = wr[kk]; float4 a4 = aq[kk];
            acc.x = fmaf(w4.x, a4.x, acc.x); acc.y = fmaf(w4.y, a4.y, acc.y);
            acc.z = fmaf(w4.z, a4.z, acc.z); acc.w = fmaf(w4.w, a4.w, acc.w);
        }
        gp[3072 + s * 3 + c] = (acc.x + acc.y) + (acc.z + acc.w) + fc2b[c];
    }
    __syncthreads();
    if (tid < 16) {
        int s = tid;
        float l0 = gp[3072 + s * 3], l1 = gp[3072 + s * 3 + 1], l2 = gp[3072 + s * 3 + 2];
        float m = fmaxf(l0, fmaxf(l1, l2));
        float e0 = __expf(l0 - m), e1 = __expf(l1 - m), e2 = __expf(l2 - m);
        float inv = 1.f / (e0 + e1 + e2);
        size_t so = ((size_t)blockIdx.x * 16 + s) * 3;
        out[so + 0] = e0 * inv;
        out[so + 1] = e1 * inv;
        out[so + 2] = e2 * inv;
    }
}

extern "C" void kernel_launch(void* const* d_in, const int* in_sizes, int n_in,
                              void* d_out, int out_size, void* d_ws, size_t ws_size,
                              hipStream_t stream) {
    (void)in_sizes; (void)n_in; (void)out_size; (void)ws_size;
    const float* x        = (const float*)d_in[0];
    const float* ea       = (const float*)d_in[1];
    const float* conv1_w  = (const float*)d_in[2];
    const float* conv1_b  = (const float*)d_in[3];
    const float* conv2_w  = (const float*)d_in[4];
    const float* conv2_b  = (const float*)d_in[5];
    const float* w_ih     = (const float*)d_in[6];
    const float* w_hh     = (const float*)d_in[7];
    const float* b_ih     = (const float*)d_in[8];
    const float* b_hh     = (const float*)d_in[9];
    const float* fc1_w    = (const float*)d_in[10];
    const float* fc1_b    = (const float*)d_in[11];
    const float* fc2_w    = (const float*)d_in[12];
    const float* fc2_b    = (const float*)d_in[13];
    const int*   ei       = (const int*)d_in[14];
    float* out = (float*)d_out;

    float* W    = (float*)d_ws;
    int2*  ent  = (int2*)(W + OFF_ENT);
    unsigned short* a1h = (unsigned short*)(W + OFF_A1);   // fp16 a1 rows
    int2*  ent2 = (int2*)(W + OFF_ENT2);
    uint2* xnd  = (uint2*)(W + OFF_ENT2);  // bf16 rows; reuses dead csr staging
    float* h2   = W + OFF_H2;              // bf16 rows; overwrites dead xnd (sequentially safe)
    unsigned short* g2h = (unsigned short*)(W + OFF_G2);   // fp16 rows
    int*   gcur = (int*)(W + OFF_GCUR);
    float* dis  = W + OFF_DIS;
    int2*  rng  = (int2*)(W + OFF_RNG);
    float* st   = W + OFF_ST;

    // init + normalization stats
    init_zero<<<26, 256, 0, stream>>>(gcur, st);
    col_sums<<<1024, 256, 0, stream>>>(x, st);
    finalize_stats<<<1, 64, 0, stream>>>(st);

    // dest-sorted CSR via two-pass counting sort (coalesced writes, no global float atomics)
    part_kernel<<<NPART, PTHR, 0, stream>>>(ei, ea, gcur, ent2);
    bucket_csr<<<NBUK, 256, 0, stream>>>(ent2, gcur, ent, rng, dis);

    // pre-scaled bf16 node features: xnd = bf16(dis * normalize(x))
    xnd_kernel<<<NN * 16 / 256, 256, 0, stream>>>(x, st, dis, xnd);

    // GCN layer 1 aggregation (full parallelism): a1 = S·xnd (fp16 out)
    gcn_gather<16><<<NN * 16 / 256, 256, 0, stream>>>(xnd, rng, ent, dis, a1h);

    // fused GEMM 1+2: h2 = bf16(dis*(relu(a1@W1 + b1)@W2)) — saves g1 round-trip
    fused_gemm12<<<NN / 64, 256, 0, stream>>>(a1h, conv1_w, conv1_b, conv2_w, dis,
                                              (unsigned short*)h2);

    // GCN layer 2 aggregation: g2 = S·h2 (fp16 out)
    gcn_gather<16><<<NN * 16 / 256, 256, 0, stream>>>((const uint2*)h2, rng, ent, dis, g2h);

    // fused LSTM + FC head: recurrence, fc1/fc2/softmax in-block, probs to out
    lstm_kernel<<<SS / 16, 512, 0, stream>>>((const __half*)g2h, conv2_b, w_hh, w_ih,
                                             b_ih, b_hh, fc1_w, fc1_b, fc2_w, fc2_b, out);
}

// Round 13
// 337.668 us; speedup vs baseline: 1.0357x; 1.0357x over previous
//
#include <hip/hip_runtime.h>
#include <hip/hip_bf16.h>
#include <hip/hip_fp16.h>

#define NN 102400      // B*T*NODES
#define DD 64
#define EE 1638400
#define L1C 96
#define L2C 64
#define TT 32
#define NODESC 400
#define BB 8
#define SS 3200        // B*NODES
#define G4 256         // 4*D

#define NBUK 400       // coarse buckets (node >> 8), NN = 400*256 exactly
#define BCAP 5120      // slots per bucket (mean 4096, sd 64 -> +16 sigma)
#define PCHUNK 2048    // 800 blocks x 512 thr
#define NPART (EE / PCHUNK)   // 800
#define PTHR 512
#define EPT (PCHUNK / PTHR)   // 4 edges per thread

// ---------------- workspace layout (floats) ----------------
#define OFF_ENT  ((size_t)0)          // NBUK*BCAP int2 = 4,096,000 floats
#define OFF_A1   ((size_t)4096000)    // NN*64 fp16 a1 rows
#define OFF_ENT2 ((size_t)26214400)   // csr staging; then xnd bf16; then h2 bf16
#define OFF_H2   ((size_t)26214400)   // NN*64 bf16 (overwrites dead xnd)
#define OFF_G2   ((size_t)32768000)   // NN*64 fp16
#define OFF_GCUR ((size_t)39321600)   // 400 cursors padded x16 ints = 6400
#define OFF_DIS  ((size_t)39328000)   // NN -> ends 39,430,400
#define OFF_RNG  ((size_t)39430400)   // NN int2 -> ends 39,635,200
#define OFF_HL   ((size_t)39635200)   // SS*64 -> ends 39,840,000
#define OFF_ST   ((size_t)39840000)   // 256 -> ends 39,840,256

typedef __attribute__((ext_vector_type(8))) _Float16 f16x8;  // 8 f16 in 4 VGPRs
typedef __attribute__((ext_vector_type(4))) float f32x4;

__device__ __forceinline__ void fma4(float4& a, float s, const float4& w) {
    a.x = fmaf(s, w.x, a.x); a.y = fmaf(s, w.y, a.y);
    a.z = fmaf(s, w.z, a.z); a.w = fmaf(s, w.w, a.w);
}
__device__ __forceinline__ float rcp_f(float x) { return __builtin_amdgcn_rcpf(x); }
__device__ __forceinline__ float sigm_f(float x) {
    x = fminf(fmaxf(x, -30.f), 30.f);
    return rcp_f(1.f + __expf(-x));
}
__device__ __forceinline__ float tanh_f(float x) {
    x = fminf(fmaxf(x, -15.f), 15.f);
    float e = __expf(2.f * x);
    return (e - 1.f) * rcp_f(e + 1.f);
}
__device__ __forceinline__ unsigned short f32_bf16_rtne(float f) {
    unsigned int u = __float_as_uint(f);
    unsigned int r = u + 0x7fffu + ((u >> 16) & 1u);
    return (unsigned short)(r >> 16);
}
__device__ __forceinline__ float bf16_f32(unsigned short h) {
    return __uint_as_float(((unsigned int)h) << 16);
}
// bf16 x4 pack/unpack (gather tables)
__device__ __forceinline__ float4 unp4(uint2 p) {
    float4 v;
    v.x = __uint_as_float(p.x << 16);
    v.y = __uint_as_float(p.x & 0xffff0000u);
    v.z = __uint_as_float(p.y << 16);
    v.w = __uint_as_float(p.y & 0xffff0000u);
    return v;
}
__device__ __forceinline__ uint2 pk4(float4 v) {
    unsigned int u0 = ((unsigned int)f32_bf16_rtne(v.y) << 16) | f32_bf16_rtne(v.x);
    unsigned int u1 = ((unsigned int)f32_bf16_rtne(v.w) << 16) | f32_bf16_rtne(v.z);
    return make_uint2(u0, u1);
}
// fp16 x4 pack/unpack (GEMM intermediates)
__device__ __forceinline__ uint2 pkh4(float4 v) {
    __half2 h0 = __floats2half2_rn(v.x, v.y);
    __half2 h1 = __floats2half2_rn(v.z, v.w);
    uint2 r;
    r.x = *(unsigned int*)&h0;
    r.y = *(unsigned int*)&h1;
    return r;
}
__device__ __forceinline__ float4 uph4(uint2 p) {
    __half2 h0 = *(__half2*)&p.x;
    __half2 h1 = *(__half2*)&p.y;
    float2 f0 = __half22float2(h0), f1 = __half22float2(h1);
    return make_float4(f0.x, f0.y, f1.x, f1.y);
}

// ---------------- init: zero bucket cursors + stats ----------------
__global__ void init_zero(int* gcur, float* st) {
    int idx = blockIdx.x * 256 + threadIdx.x;
    if (idx < NBUK * 16) gcur[idx] = 0;
    if (blockIdx.x == 0 && threadIdx.x < 128) st[threadIdx.x] = 0.f;
}

// ---------------- normalization stats ----------------
__global__ __launch_bounds__(256) void col_sums(const float* __restrict__ x, float* __restrict__ st) {
    int c = threadIdx.x & 63;
    size_t i = (size_t)blockIdx.x * 256 + threadIdx.x;
    size_t stride = (size_t)gridDim.x * 256;
    float s = 0.f, q = 0.f;
    for (size_t e = i; e < (size_t)NN * 64; e += stride) {
        float v = x[e]; s += v; q = fmaf(v, v, q);
    }
    __shared__ float ls[128];
    if (threadIdx.x < 128) ls[threadIdx.x] = 0.f;
    __syncthreads();
    atomicAdd(&ls[c], s); atomicAdd(&ls[64 + c], q);
    __syncthreads();
    if (threadIdx.x < 128) atomicAdd(&st[threadIdx.x], ls[threadIdx.x]);
}

__global__ void finalize_stats(float* st) {
    int c = threadIdx.x;
    if (c < 64) {
        float s = st[c], q = st[64 + c];
        float mean = s / (float)NN;
        float var = (q - s * s / (float)NN) / (float)(NN - 1);
        st[128 + c] = mean;
        st[192 + c] = rsqrtf(fmaxf(var, 1e-20f));
    }
}

// ---------------- xnd = bf16( dis[n] * normalize(x[n]) ) ----------------
__global__ __launch_bounds__(256) void xnd_kernel(const float* __restrict__ x, const float* __restrict__ st,
                                                  const float* __restrict__ dis, uint2* __restrict__ xnd) {
    size_t i = (size_t)blockIdx.x * 256 + threadIdx.x;   // float4 index
    int n = (int)(i >> 4), q = (int)(i & 15);
    float4 v = ((const float4*)x)[i];
    float4 mean4 = ((const float4*)(st + 128))[q];
    float4 istd4 = ((const float4*)(st + 192))[q];
    float dn = dis[n];
    v.x = (v.x - mean4.x) * istd4.x * dn;
    v.y = (v.y - mean4.y) * istd4.y * dn;
    v.z = (v.z - mean4.z) * istd4.z * dn;
    v.w = (v.w - mean4.w) * istd4.w * dn;
    xnd[i] = pk4(v);
}

// ---------------- pass 1: coarse bucket partition, LDS-staged coalesced writes ----------------
__global__ __launch_bounds__(PTHR) void part_kernel(const int* __restrict__ ei, const float* __restrict__ ea,
                                                    int* __restrict__ gcur, int2* __restrict__ ent2) {
    __shared__ int lhist[NBUK];        // counts, then reused as scatter cursors
    __shared__ int lofs[NBUK];         // block-local exclusive offsets
    __shared__ int lbase[NBUK];        // global within-bucket base (from gcur)
    __shared__ int scn[PTHR];          // scan workspace
    __shared__ int2 stage[PCHUNK];     // 16 KB bucket-sorted staging
    __shared__ int  gdst[PCHUNK];      // 8 KB absolute destinations (-1 = drop)
    const int tid = threadIdx.x;
    const int e0 = blockIdx.x * PCHUNK;
    for (int i = tid; i < NBUK; i += PTHR) lhist[i] = 0;
    __syncthreads();
    int   dv[EPT]; int sv[EPT]; float wvv[EPT];
    #pragma unroll
    for (int i = 0; i < EPT; ++i) {
        int e = e0 + i * PTHR + tid;
        dv[i]  = ei[EE + e];
        sv[i]  = ei[e];
        wvv[i] = fabsf(ea[2 * (size_t)e]);
        atomicAdd(&lhist[dv[i] >> 8], 1);
    }
    __syncthreads();
    // exclusive prefix over bucket counts (Hillis-Steele over PTHR lanes)
    scn[tid] = (tid < NBUK) ? lhist[tid] : 0;
    __syncthreads();
    for (int d = 1; d < PTHR; d <<= 1) {
        int t = (tid >= d) ? scn[tid - d] : 0;
        __syncthreads();
        scn[tid] += t;
        __syncthreads();
    }
    if (tid < NBUK) {
        lofs[tid]  = scn[tid] - lhist[tid];                  // exclusive
        lbase[tid] = atomicAdd(&gcur[tid * 16], lhist[tid]); // reserve global run
        lhist[tid] = 0;                                      // reuse as cursor
    }
    __syncthreads();
    // scatter into bucket-sorted LDS staging + precompute global destination
    #pragma unroll
    for (int i = 0; i < EPT; ++i) {
        int d = dv[i];
        int b = d >> 8;
        int li = atomicAdd(&lhist[b], 1);
        int pos = lofs[b] + li;
        stage[pos] = make_int2(sv[i] | ((d & 255) << 24), __float_as_int(wvv[i]));
        int gp_ = lbase[b] + li;
        gdst[pos] = (gp_ < BCAP) ? (b * BCAP + gp_) : -1;
    }
    __syncthreads();
    // write out: consecutive lanes cover consecutive addresses within segments
    for (int i = tid; i < PCHUNK; i += PTHR) {
        int g = gdst[i];
        if (g >= 0) ent2[g] = stage[i];
    }
}

// ---------------- pass 2: per-bucket counting sort in LDS + rng + dis ----------------
// v2: sort into a 40 KB LDS buffer, then write ent fully coalesced.
__global__ __launch_bounds__(256) void bucket_csr(const int2* __restrict__ ent2, const int* __restrict__ gcur,
                                                  int2* __restrict__ ent, int2* __restrict__ rng,
                                                  float* __restrict__ dis) {
    __shared__ int nhist[256];
    __shared__ int scn[256];
    __shared__ float wsum[256];
    __shared__ int pcur[256];
    __shared__ int2 sorted[BCAP];   // 40 KB
    const int tid = threadIdx.x;
    const int b = blockIdx.x;
    const int base = b * BCAP;
    int cnt = gcur[b * 16];
    if (cnt > BCAP) cnt = BCAP;
    nhist[tid] = 0;
    wsum[tid] = 0.f;
    __syncthreads();
    for (int e = tid; e < cnt; e += 256) {
        int2 en = ent2[base + e];
        int dl = ((unsigned)en.x) >> 24;
        atomicAdd(&nhist[dl], 1);
        atomicAdd(&wsum[dl], __int_as_float(en.y));
    }
    __syncthreads();
    int c = nhist[tid];
    scn[tid] = c;
    __syncthreads();
    for (int d = 1; d < 256; d <<= 1) {
        int t = (tid >= d) ? scn[tid - d] : 0;
        __syncthreads();
        scn[tid] += t;
        __syncthreads();
    }
    int ps = scn[tid] - c;                       // exclusive prefix within bucket
    rng[b * 256 + tid] = make_int2(base + ps, base + ps + c);
    dis[b * 256 + tid] = rsqrtf(1.f + wsum[tid]); // self-loop weight 1 folded in
    pcur[tid] = ps;
    __syncthreads();
    for (int e = tid; e < cnt; e += 256) {
        int2 en = ent2[base + e];
        int dl = ((unsigned)en.x) >> 24;
        int local = atomicAdd(&pcur[dl], 1);
        sorted[local] = make_int2(en.x & 0xFFFFFF, en.y);
    }
    __syncthreads();
    // coalesced write-out
    for (int e = tid; e < cnt; e += 256)
        ent[base + e] = sorted[e];
}

// ---------------- fused MFMA GEMM 1+2: h2 = bf16(dis*(relu(a1@W1 + b1)@W2)) ----------------
#define G1_LD 72
#define G2_LD 104
__global__ __launch_bounds__(256) void fused_gemm12(
    const unsigned short* __restrict__ A, const float* __restrict__ W1,
    const float* __restrict__ b1v, const float* __restrict__ W2,
    const float* __restrict__ dscale, unsigned short* __restrict__ h2out)
{
    __shared__ __align__(16) _Float16 As[64 * G1_LD];    // a1 rows f16 (9.2 KB)
    __shared__ __align__(16) _Float16 G1s[64 * G2_LD];   // relu(g1+b1) f16 (13.3 KB)
    __shared__ float ds[64];
    const int tid  = threadIdx.x;
    const int lane = tid & 63;
    const int wv   = tid >> 6;          // wave 0..3
    const int n15  = lane & 15;
    const int quad = lane >> 4;
    const size_t row0 = (size_t)blockIdx.x * 64;

    if (tid < 64) ds[tid] = dscale[row0 + tid];

    // ---- W1 frags: ctiles {wv, wv+4 if wv<2} covering 0..5; hi + lo*2048 f16 ----
    const int nt1 = (wv < 2) ? 2 : 1;
    f16x8 w1h[2][2], w1l[2][2];
    float b1c[2] = {0.f, 0.f};
    #pragma unroll
    for (int t = 0; t < 2; ++t) {
        if (t < nt1) {
            const int col = (wv + 4 * t) * 16 + n15;
            b1c[t] = b1v[col];
            #pragma unroll
            for (int kc = 0; kc < 2; ++kc) {
                #pragma unroll
                for (int j = 0; j < 8; ++j) {
                    float w = W1[(size_t)(kc * 32 + quad * 8 + j) * 96 + col];
                    _Float16 h = (_Float16)w;
                    w1h[t][kc][j] = h;
                    w1l[t][kc][j] = (_Float16)((w - (float)h) * 2048.f);
                }
            }
        }
    }
    // ---- W2 frags: ctile wv, col = wv*16+n15, 3 k-chunks ----
    f16x8 w2h[3], w2l[3];
    {
        const int col = wv * 16 + n15;
        #pragma unroll
        for (int kc = 0; kc < 3; ++kc) {
            #pragma unroll
            for (int j = 0; j < 8; ++j) {
                float w = W2[(size_t)(kc * 32 + quad * 8 + j) * 64 + col];
                _Float16 h = (_Float16)w;
                w2h[kc][j] = h;
                w2l[kc][j] = (_Float16)((w - (float)h) * 2048.f);
            }
        }
    }

    // ---- stage a1 rows (already fp16): coalesced uint2 copy ----
    for (int i = tid; i < 64 * 16; i += 256) {
        int r = i >> 4, c4 = i & 15;
        uint2 p = *(const uint2*)(A + (row0 + r) * 64 + c4 * 4);
        *(uint2*)(As + r * G1_LD + c4 * 4) = p;
    }
    __syncthreads();

    // ---- phase B: g1 = a1 @ W1, relu(g1+b1) -> G1s f16 ----
    {
        f32x4 acc1[2][4], accl1[2][4];
        #pragma unroll
        for (int t = 0; t < 2; ++t)
            #pragma unroll
            for (int rt = 0; rt < 4; ++rt) {
                acc1[t][rt]  = (f32x4){0.f, 0.f, 0.f, 0.f};
                accl1[t][rt] = (f32x4){0.f, 0.f, 0.f, 0.f};
            }
        #pragma unroll
        for (int kc = 0; kc < 2; ++kc) {
            #pragma unroll
            for (int rt = 0; rt < 4; ++rt) {
                f16x8 a = *(const f16x8*)(As + (rt * 16 + n15) * G1_LD + kc * 32 + quad * 8);
                acc1[0][rt]  = __builtin_amdgcn_mfma_f32_16x16x32_f16(a, w1h[0][kc], acc1[0][rt],  0, 0, 0);
                accl1[0][rt] = __builtin_amdgcn_mfma_f32_16x16x32_f16(a, w1l[0][kc], accl1[0][rt], 0, 0, 0);
                if (nt1 == 2) {
                    acc1[1][rt]  = __builtin_amdgcn_mfma_f32_16x16x32_f16(a, w1h[1][kc], acc1[1][rt],  0, 0, 0);
                    accl1[1][rt] = __builtin_amdgcn_mfma_f32_16x16x32_f16(a, w1l[1][kc], accl1[1][rt], 0, 0, 0);
                }
            }
        }
        #pragma unroll
        for (int t = 0; t < 2; ++t) {
            if (t < nt1) {
                const int col = (wv + 4 * t) * 16 + n15;
                #pragma unroll
                for (int rt = 0; rt < 4; ++rt) {
                    f32x4 c = acc1[t][rt] + accl1[t][rt] * (1.f / 2048.f);
                    #pragma unroll
                    for (int r = 0; r < 4; ++r) {
                        int row = rt * 16 + quad * 4 + r;
                        G1s[row * G2_LD + col] = (_Float16)fmaxf(c[r] + b1c[t], 0.f);
                    }
                }
            }
        }
    }
    __syncthreads();

    // ---- phase C: h2 = bf16(dis * (relu_g1 @ W2)) ----
    {
        f32x4 acc[4], accl[4];
        #pragma unroll
        for (int rt = 0; rt < 4; ++rt) {
            acc[rt]  = (f32x4){0.f, 0.f, 0.f, 0.f};
            accl[rt] = (f32x4){0.f, 0.f, 0.f, 0.f};
        }
        #pragma unroll
        for (int kc = 0; kc < 3; ++kc) {
            #pragma unroll
            for (int rt = 0; rt < 4; ++rt) {
                f16x8 a = *(const f16x8*)(G1s + (rt * 16 + n15) * G2_LD + kc * 32 + quad * 8);
                acc[rt]  = __builtin_amdgcn_mfma_f32_16x16x32_f16(a, w2h[kc], acc[rt],  0, 0, 0);
                accl[rt] = __builtin_amdgcn_mfma_f32_16x16x32_f16(a, w2l[kc], accl[rt], 0, 0, 0);
            }
        }
        const int col = wv * 16 + n15;
        #pragma unroll
        for (int rt = 0; rt < 4; ++rt) {
            f32x4 c = acc[rt] + accl[rt] * (1.f / 2048.f);
            #pragma unroll
            for (int r = 0; r < 4; ++r) {
                int row = rt * 16 + quad * 4 + r;
                float v = c[r] * ds[row];
                h2out[(row0 + row) * 64 + col] = f32_bf16_rtne(v);
            }
        }
    }
}

// ---------------- GCN aggregation: gather over packed CSR (rng int2 ranges) ----------------
template<int C4>
__global__ __launch_bounds__(256) void gcn_gather(const uint2* __restrict__ h, const int2* __restrict__ rng,
                                                  const int2* __restrict__ ent, const float* __restrict__ dis,
                                                  unsigned short* __restrict__ g) {
    unsigned int idx = blockIdx.x * 256 + threadIdx.x;
    unsigned int n = idx / C4, q = idx % C4;
    float4 acc = unp4(h[(size_t)n * C4 + q]);
    int2 r = rng[n];
    int e = r.x;
    for (; e + 8 <= r.y; e += 8) {
        int2 en0 = ent[e],     en1 = ent[e + 1], en2 = ent[e + 2], en3 = ent[e + 3];
        int2 en4 = ent[e + 4], en5 = ent[e + 5], en6 = ent[e + 6], en7 = ent[e + 7];
        uint2 v0 = h[(size_t)en0.x * C4 + q];
        uint2 v1 = h[(size_t)en1.x * C4 + q];
        uint2 v2 = h[(size_t)en2.x * C4 + q];
        uint2 v3 = h[(size_t)en3.x * C4 + q];
        uint2 v4 = h[(size_t)en4.x * C4 + q];
        uint2 v5 = h[(size_t)en5.x * C4 + q];
        uint2 v6 = h[(size_t)en6.x * C4 + q];
        uint2 v7 = h[(size_t)en7.x * C4 + q];
        fma4(acc, __int_as_float(en0.y), unp4(v0));
        fma4(acc, __int_as_float(en1.y), unp4(v1));
        fma4(acc, __int_as_float(en2.y), unp4(v2));
        fma4(acc, __int_as_float(en3.y), unp4(v3));
        fma4(acc, __int_as_float(en4.y), unp4(v4));
        fma4(acc, __int_as_float(en5.y), unp4(v5));
        fma4(acc, __int_as_float(en6.y), unp4(v6));
        fma4(acc, __int_as_float(en7.y), unp4(v7));
    }
    for (; e + 4 <= r.y; e += 4) {
        int2 en0 = ent[e], en1 = ent[e + 1], en2 = ent[e + 2], en3 = ent[e + 3];
        uint2 v0 = h[(size_t)en0.x * C4 + q];
        uint2 v1 = h[(size_t)en1.x * C4 + q];
        uint2 v2 = h[(size_t)en2.x * C4 + q];
        uint2 v3 = h[(size_t)en3.x * C4 + q];
        fma4(acc, __int_as_float(en0.y), unp4(v0));
        fma4(acc, __int_as_float(en1.y), unp4(v1));
        fma4(acc, __int_as_float(en2.y), unp4(v2));
        fma4(acc, __int_as_float(en3.y), unp4(v3));
    }
    for (; e < r.y; ++e) {
        int2 en = ent[e];
        uint2 v = h[(size_t)en.x * C4 + q];
        fma4(acc, __int_as_float(en.y), unp4(v));
    }
    float dn = dis[n];
    acc.x *= dn; acc.y *= dn; acc.z *= dn; acc.w *= dn;
    *(uint2*)(g + (size_t)n * (C4 * 4) + q * 4) = pkh4(acc);
}

// ---------------- fused LSTM: x-path GEMM + recurrence, all MFMA (f16, split planes) ----------------
// v3 (REVERTED from R12 head-fusion: fusing fc1/fc2 pushed VGPR 88->120 and
// slowed the whole main loop 46->71us — register pressure poisoned codegen).
// 8 waves (512 thr), 2 gate-tiles per wave. Best measured variant (~42us).
#define XP_LD 72   // xpack seq-row stride (halves): 4*(n15+quad) bank spread
#define HP_LD2 72  // h plane row stride (halves)
#define GP_LD 258  // gp row stride (floats): store banks 8q+2r+n15 = 2/bank floor

__global__ __launch_bounds__(512, 1) void lstm_kernel(
    const __half* __restrict__ g2, const float* __restrict__ cb2,
    const float* __restrict__ whh, const float* __restrict__ wih,
    const float* __restrict__ bih, const float* __restrict__ bhh,
    float* __restrict__ hlast)
{
    __shared__ __align__(16) _Float16 xpack[32 * 16 * XP_LD];  // 73.7 KB
    __shared__ __align__(16) _Float16 hhi[16 * HP_LD2];        // 2.25 KB
    __shared__ __align__(16) _Float16 hlo[16 * HP_LD2];        // 2.25 KB
    __shared__ float gp[16 * GP_LD];                           // 16.1 KB
    const int tid  = threadIdx.x;       // 0..511
    const int lane = tid & 63;
    const int wv   = tid >> 6;          // wave 0..7
    const int n15  = lane & 15;         // A: seq m / B: gate-in-tile n
    const int quad = lane >> 4;         // k sub-block
    const int ja   = lane;              // activation hidden unit 0..63

    // ---- loop-invariant B-frags for 2 gate tiles: gate = (wv+8*tl)*16+n15 ----
    f16x8 whh_h[2][2], whh_l[2][2], wih_h[2][2], wih_l[2][2];  // [tile][kc]
    #pragma unroll
    for (int tl = 0; tl < 2; ++tl) {
        const int gate = (wv + 8 * tl) * 16 + n15;
        const float* wp = whh + (size_t)gate * 64 + quad * 8;
        const float* xp = wih + (size_t)gate * 64 + quad * 8;
        #pragma unroll
        for (int kc = 0; kc < 2; ++kc) {
            #pragma unroll
            for (int j = 0; j < 8; ++j) {
                float w = wp[kc * 32 + j];
                _Float16 h = (_Float16)w;
                whh_h[tl][kc][j] = h;
                whh_l[tl][kc][j] = (_Float16)((w - (float)h) * 2048.f);
                float v = xp[kc * 32 + j];
                _Float16 g = (_Float16)v;
                wih_h[tl][kc][j] = g;
                wih_l[tl][kc][j] = (_Float16)((v - (float)g) * 2048.f);
            }
        }
    }

    // ---- activation-phase gate biases (b_ih + b_hh), f32 (depend on ja only) ----
    const float bi_i = bih[ja]        + bhh[ja];
    const float bi_f = bih[64 + ja]   + bhh[64 + ja];
    const float bi_g = bih[128 + ja]  + bhh[128 + ja];
    const float bi_o = bih[192 + ja]  + bhh[192 + ja];

    // ---- prologue: stage xr = relu(g2 + conv2_b) into xpack, fully coalesced ----
    {
        const int s0 = blockIdx.x * 16;          // 400 % 16 == 0: block never straddles b_
        const int b_ = s0 / NODESC;
        const int node0 = s0 - b_ * NODESC;
        const int r  = (tid >> 4) & 15;          // seq row (fixed per thread)
        const int c4 = tid & 15;                 // 4-half group within row
        const int t0 = tid >> 8;                 // 0..1; t = t0 + 2*i
        float4 bias4 = *(const float4*)(cb2 + c4 * 4);
        _Float16* dst = xpack + r * XP_LD + c4 * 4;
        const __half* src = g2 + ((size_t)(b_ * TT + t0) * NODESC + node0 + r) * 64 + c4 * 4;
        #pragma unroll
        for (int i = 0; i < 16; ++i) {
            uint2 p = *(const uint2*)(src + (size_t)i * 2 * NODESC * 64);
            float4 v = uph4(p);
            v.x = fmaxf(v.x + bias4.x, 0.f);
            v.y = fmaxf(v.y + bias4.y, 0.f);
            v.z = fmaxf(v.z + bias4.z, 0.f);
            v.w = fmaxf(v.w + bias4.w, 0.f);
            *(uint2*)(dst + (size_t)(t0 + i * 2) * (16 * XP_LD)) = pkh4(v);
        }
    }

    // ---- init h = 0 ----
    for (int i = tid; i < 16 * HP_LD2; i += 512) { hhi[i] = (_Float16)0.f; hlo[i] = (_Float16)0.f; }
    float cA_reg = 0.f, hA = 0.f;   // state for (qa = wv, ja)
    float cB_reg = 0.f, hB = 0.f;   // state for (qa = wv+8, ja)
    __syncthreads();

    const int xbase = n15 * XP_LD + quad * 8;    // halves, 16B-aligned
    const int hbase = n15 * HP_LD2 + quad * 8;

    for (int t = 0; t < TT; ++t) {
        // ---- dot phase: 6 A-frag reads shared by 2 tiles, 20 MFMAs, 6 chains ----
        f32x4 cmA  = {0.f,0.f,0.f,0.f}, clA0 = {0.f,0.f,0.f,0.f}, clA1 = {0.f,0.f,0.f,0.f};
        f32x4 cmB  = {0.f,0.f,0.f,0.f}, clB0 = {0.f,0.f,0.f,0.f}, clB1 = {0.f,0.f,0.f,0.f};
        const _Float16* xrow = xpack + (size_t)t * (16 * XP_LD);
        {
            f16x8 ax0 = *(const f16x8*)(xrow + xbase);
            f16x8 ah0 = *(const f16x8*)(hhi + hbase);
            f16x8 al0 = *(const f16x8*)(hlo + hbase);
            f16x8 ax1 = *(const f16x8*)(xrow + xbase + 32);
            f16x8 ah1 = *(const f16x8*)(hhi + hbase + 32);
            f16x8 al1 = *(const f16x8*)(hlo + hbase + 32);
            cmA  = __builtin_amdgcn_mfma_f32_16x16x32_f16(ax0, wih_h[0][0], cmA,  0, 0, 0);
            cmB  = __builtin_amdgcn_mfma_f32_16x16x32_f16(ax0, wih_h[1][0], cmB,  0, 0, 0);
            clA0 = __builtin_amdgcn_mfma_f32_16x16x32_f16(ax0, wih_l[0][0], clA0, 0, 0, 0);
            clB0 = __builtin_amdgcn_mfma_f32_16x16x32_f16(ax0, wih_l[1][0], clB0, 0, 0, 0);
            clA1 = __builtin_amdgcn_mfma_f32_16x16x32_f16(ax1, wih_l[0][1], clA1, 0, 0, 0);
            clB1 = __builtin_amdgcn_mfma_f32_16x16x32_f16(ax1, wih_l[1][1], clB1, 0, 0, 0);
            cmA  = __builtin_amdgcn_mfma_f32_16x16x32_f16(ah0, whh_h[0][0], cmA,  0, 0, 0);
            cmB  = __builtin_amdgcn_mfma_f32_16x16x32_f16(ah0, whh_h[1][0], cmB,  0, 0, 0);
            clA0 = __builtin_amdgcn_mfma_f32_16x16x32_f16(al0, whh_h[0][0], clA0, 0, 0, 0);
            clB0 = __builtin_amdgcn_mfma_f32_16x16x32_f16(al0, whh_h[1][0], clB0, 0, 0, 0);
            clA1 = __builtin_amdgcn_mfma_f32_16x16x32_f16(al1, whh_h[0][1], clA1, 0, 0, 0);
            clB1 = __builtin_amdgcn_mfma_f32_16x16x32_f16(al1, whh_h[1][1], clB1, 0, 0, 0);
            cmA  = __builtin_amdgcn_mfma_f32_16x16x32_f16(ax1, wih_h[0][1], cmA,  0, 0, 0);
            cmB  = __builtin_amdgcn_mfma_f32_16x16x32_f16(ax1, wih_h[1][1], cmB,  0, 0, 0);
            clA0 = __builtin_amdgcn_mfma_f32_16x16x32_f16(ah0, whh_l[0][0], clA0, 0, 0, 0);
            clB0 = __builtin_amdgcn_mfma_f32_16x16x32_f16(ah0, whh_l[1][0], clB0, 0, 0, 0);
            clA1 = __builtin_amdgcn_mfma_f32_16x16x32_f16(ah1, whh_l[0][1], clA1, 0, 0, 0);
            clB1 = __builtin_amdgcn_mfma_f32_16x16x32_f16(ah1, whh_l[1][1], clB1, 0, 0, 0);
            cmA  = __builtin_amdgcn_mfma_f32_16x16x32_f16(ah1, whh_h[0][1], cmA,  0, 0, 0);
            cmB  = __builtin_amdgcn_mfma_f32_16x16x32_f16(ah1, whh_h[1][1], cmB,  0, 0, 0);
        }
        f32x4 cA = cmA + (clA0 + clA1) * (1.f / 2048.f);
        f32x4 cB = cmB + (clB0 + clB1) * (1.f / 2048.f);
        // C: lane holds seqs m = quad*4+r; columns wv*16+n15 and (wv+8)*16+n15
        #pragma unroll
        for (int r = 0; r < 4; ++r) {
            gp[(quad * 4 + r) * GP_LD + wv * 16 + n15]       = cA[r];
            gp[(quad * 4 + r) * GP_LD + (wv + 8) * 16 + n15] = cB[r];
        }
        __syncthreads();

        // ---- activation phase: thread handles (wv, ja) and (wv+8, ja) ----
        {
            const int qa = wv;
            float gi = gp[qa * GP_LD + ja]        + bi_i;
            float gf = gp[qa * GP_LD + 64 + ja]   + bi_f;
            float gg = gp[qa * GP_LD + 128 + ja]  + bi_g;
            float go = gp[qa * GP_LD + 192 + ja]  + bi_o;
            cA_reg = sigm_f(gf) * cA_reg + sigm_f(gi) * tanh_f(gg);
            hA = sigm_f(go) * tanh_f(cA_reg);
            _Float16 hh = (_Float16)hA;
            hhi[qa * HP_LD2 + ja] = hh;
            hlo[qa * HP_LD2 + ja] = (_Float16)((hA - (float)hh) * 2048.f);
        }
        {
            const int qa = wv + 8;
            float gi = gp[qa * GP_LD + ja]        + bi_i;
            float gf = gp[qa * GP_LD + 64 + ja]   + bi_f;
            float gg = gp[qa * GP_LD + 128 + ja]  + bi_g;
            float go = gp[qa * GP_LD + 192 + ja]  + bi_o;
            cB_reg = sigm_f(gf) * cB_reg + sigm_f(gi) * tanh_f(gg);
            hB = sigm_f(go) * tanh_f(cB_reg);
            _Float16 hh = (_Float16)hB;
            hhi[qa * HP_LD2 + ja] = hh;
            hlo[qa * HP_LD2 + ja] = (_Float16)((hB - (float)hh) * 2048.f);
        }
        __syncthreads();
    }
    hlast[((size_t)blockIdx.x * 16 + wv) * 64 + ja]     = hA;
    hlast[((size_t)blockIdx.x * 16 + wv + 8) * 64 + ja] = hB;
}

// ---------------- FC head + softmax ----------------
__global__ __launch_bounds__(128) void head_kernel(const float* __restrict__ hl,
                                                   const float* __restrict__ w1, const float* __restrict__ b1,
                                                   const float* __restrict__ w2, const float* __restrict__ b2,
                                                   float* __restrict__ out) {
    __shared__ float hrow[64];
    __shared__ float a1[128];
    __shared__ float lg[3];
    int s = blockIdx.x, tid = threadIdx.x;
    if (tid < 64) hrow[tid] = hl[(size_t)s * 64 + tid];
    __syncthreads();
    {
        const float4* wr = (const float4*)(w1 + (size_t)tid * 64);
        const float4* hq = (const float4*)hrow;
        float4 acc = make_float4(0.f, 0.f, 0.f, 0.f);
        #pragma unroll
        for (int k = 0; k < 16; ++k) {
            float4 wv = wr[k]; float4 hv = hq[k];
            acc.x = fmaf(wv.x, hv.x, acc.x); acc.y = fmaf(wv.y, hv.y, acc.y);
            acc.z = fmaf(wv.z, hv.z, acc.z); acc.w = fmaf(wv.w, hv.w, acc.w);
        }
        a1[tid] = fmaxf((acc.x + acc.y) + (acc.z + acc.w) + b1[tid], 0.f);
    }
    __syncthreads();
    if (tid < 3) {
        const float4* wr = (const float4*)(w2 + (size_t)tid * 128);
        const float4* aq = (const float4*)a1;
        float4 acc = make_float4(0.f, 0.f, 0.f, 0.f);
        #pragma unroll
        for (int k = 0; k < 32; ++k) {
            float4 wv = wr[k]; float4 av = aq[k];
            acc.x = fmaf(wv.x, av.x, acc.x); acc.y = fmaf(wv.y, av.y, acc.y);
            acc.z = fmaf(wv.z, av.z, acc.z); acc.w = fmaf(wv.w, av.w, acc.w);
        }
        lg[tid] = (acc.x + acc.y) + (acc.z + acc.w) + b2[tid];
    }
    __syncthreads();
    if (tid == 0) {
        float m = fmaxf(lg[0], fmaxf(lg[1], lg[2]));
        float e0 = __expf(lg[0] - m), e1 = __expf(lg[1] - m), e2 = __expf(lg[2] - m);
        float inv = 1.f / (e0 + e1 + e2);
        out[(size_t)s * 3 + 0] = e0 * inv;
        out[(size_t)s * 3 + 1] = e1 * inv;
        out[(size_t)s * 3 + 2] = e2 * inv;
    }
}

extern "C" void kernel_launch(void* const* d_in, const int* in_sizes, int n_in,
                              void* d_out, int out_size, void* d_ws, size_t ws_size,
                              hipStream_t stream) {
    (void)in_sizes; (void)n_in; (void)out_size; (void)ws_size;
    const float* x        = (const float*)d_in[0];
    const float* ea       = (const float*)d_in[1];
    const float* conv1_w  = (const float*)d_in[2];
    const float* conv1_b  = (const float*)d_in[3];
    const float* conv2_w  = (const float*)d_in[4];
    const float* conv2_b  = (const float*)d_in[5];
    const float* w_ih     = (const float*)d_in[6];
    const float* w_hh     = (const float*)d_in[7];
    const float* b_ih     = (const float*)d_in[8];
    const float* b_hh     = (const float*)d_in[9];
    const float* fc1_w    = (const float*)d_in[10];
    const float* fc1_b    = (const float*)d_in[11];
    const float* fc2_w    = (const float*)d_in[12];
    const float* fc2_b    = (const float*)d_in[13];
    const int*   ei       = (const int*)d_in[14];
    float* out = (float*)d_out;

    float* W    = (float*)d_ws;
    int2*  ent  = (int2*)(W + OFF_ENT);
    unsigned short* a1h = (unsigned short*)(W + OFF_A1);   // fp16 a1 rows
    int2*  ent2 = (int2*)(W + OFF_ENT2);
    uint2* xnd  = (uint2*)(W + OFF_ENT2);  // bf16 rows; reuses dead csr staging
    float* h2   = W + OFF_H2;              // bf16 rows; overwrites dead xnd (sequentially safe)
    unsigned short* g2h = (unsigned short*)(W + OFF_G2);   // fp16 rows
    int*   gcur = (int*)(W + OFF_GCUR);
    float* dis  = W + OFF_DIS;
    int2*  rng  = (int2*)(W + OFF_RNG);
    float* hl   = W + OFF_HL;
    float* st   = W + OFF_ST;

    // init + normalization stats
    init_zero<<<26, 256, 0, stream>>>(gcur, st);
    col_sums<<<1024, 256, 0, stream>>>(x, st);
    finalize_stats<<<1, 64, 0, stream>>>(st);

    // dest-sorted CSR via two-pass counting sort (coalesced writes, no global float atomics)
    part_kernel<<<NPART, PTHR, 0, stream>>>(ei, ea, gcur, ent2);
    bucket_csr<<<NBUK, 256, 0, stream>>>(ent2, gcur, ent, rng, dis);

    // pre-scaled bf16 node features: xnd = bf16(dis * normalize(x))
    xnd_kernel<<<NN * 16 / 256, 256, 0, stream>>>(x, st, dis, xnd);

    // GCN layer 1 aggregation (full parallelism): a1 = S·xnd (fp16 out)
    gcn_gather<16><<<NN * 16 / 256, 256, 0, stream>>>(xnd, rng, ent, dis, a1h);

    // fused GEMM 1+2: h2 = bf16(dis*(relu(a1@W1 + b1)@W2)) — saves g1 round-trip
    fused_gemm12<<<NN / 64, 256, 0, stream>>>(a1h, conv1_w, conv1_b, conv2_w, dis,
                                              (unsigned short*)h2);

    // GCN layer 2 aggregation: g2 = S·h2 (fp16 out)
    gcn_gather<16><<<NN * 16 / 256, 256, 0, stream>>>((const uint2*)h2, rng, ent, dis, g2h);

    // fused LSTM v3: x-path GEMM + recurrence, all MFMA f16 (head fusion reverted)
    lstm_kernel<<<SS / 16, 512, 0, stream>>>((const __half*)g2h, conv2_b, w_hh, w_ih,
                                             b_ih, b_hh, hl);

    // FC head + softmax
    head_kernel<<<SS, 128, 0, stream>>>(hl, fc1_w, fc1_b, fc2_w, fc2_b, out);
}

// Round 14
// 334.606 us; speedup vs baseline: 1.0452x; 1.0092x over previous
//
#include <hip/hip_runtime.h>
#include <hip/hip_bf16.h>
#include <hip/hip_fp16.h>

#define NN 102400      // B*T*NODES
#define DD 64
#define EE 1638400
#define L1C 96
#define L2C 64
#define TT 32
#define NODESC 400
#define BB 8
#define SS 3200        // B*NODES
#define G4 256         // 4*D

#define NBUK 400       // coarse buckets (node >> 8), NN = 400*256 exactly
#define BCAP 5120      // slots per bucket (mean 4096, sd 64 -> +16 sigma)
#define PCHUNK 2048    // 800 blocks x 512 thr
#define NPART (EE / PCHUNK)   // 800
#define PTHR 512
#define EPT (PCHUNK / PTHR)   // 4 edges per thread
#define EPB (BCAP / 256)      // 20 entries per thread in bucket_csr

// ---------------- workspace layout (floats) ----------------
#define OFF_ENT  ((size_t)0)          // NBUK*BCAP int2 = 4,096,000 floats
#define OFF_A1   ((size_t)4096000)    // NN*64 fp16 a1 rows
#define OFF_ENT2 ((size_t)26214400)   // csr staging; then xnd bf16; then h2 bf16
#define OFF_H2   ((size_t)26214400)   // NN*64 bf16 (overwrites dead xnd)
#define OFF_G2   ((size_t)32768000)   // NN*64 fp16
#define OFF_GCUR ((size_t)39321600)   // 400 cursors padded x16 ints = 6400
#define OFF_DIS  ((size_t)39328000)   // NN -> ends 39,430,400
#define OFF_RNG  ((size_t)39430400)   // NN int2 -> ends 39,635,200
#define OFF_HL   ((size_t)39635200)   // SS*64 -> ends 39,840,000
#define OFF_ST   ((size_t)39840000)   // 256 -> ends 39,840,256

typedef __attribute__((ext_vector_type(8))) _Float16 f16x8;  // 8 f16 in 4 VGPRs
typedef __attribute__((ext_vector_type(4))) float f32x4;

__device__ __forceinline__ void fma4(float4& a, float s, const float4& w) {
    a.x = fmaf(s, w.x, a.x); a.y = fmaf(s, w.y, a.y);
    a.z = fmaf(s, w.z, a.z); a.w = fmaf(s, w.w, a.w);
}
__device__ __forceinline__ float rcp_f(float x) { return __builtin_amdgcn_rcpf(x); }
__device__ __forceinline__ float sigm_f(float x) {
    x = fminf(fmaxf(x, -30.f), 30.f);
    return rcp_f(1.f + __expf(-x));
}
__device__ __forceinline__ float tanh_f(float x) {
    x = fminf(fmaxf(x, -15.f), 15.f);
    float e = __expf(2.f * x);
    return (e - 1.f) * rcp_f(e + 1.f);
}
__device__ __forceinline__ unsigned short f32_bf16_rtne(float f) {
    unsigned int u = __float_as_uint(f);
    unsigned int r = u + 0x7fffu + ((u >> 16) & 1u);
    return (unsigned short)(r >> 16);
}
__device__ __forceinline__ float bf16_f32(unsigned short h) {
    return __uint_as_float(((unsigned int)h) << 16);
}
// bf16 x4 pack/unpack (gather tables)
__device__ __forceinline__ float4 unp4(uint2 p) {
    float4 v;
    v.x = __uint_as_float(p.x << 16);
    v.y = __uint_as_float(p.x & 0xffff0000u);
    v.z = __uint_as_float(p.y << 16);
    v.w = __uint_as_float(p.y & 0xffff0000u);
    return v;
}
__device__ __forceinline__ uint2 pk4(float4 v) {
    unsigned int u0 = ((unsigned int)f32_bf16_rtne(v.y) << 16) | f32_bf16_rtne(v.x);
    unsigned int u1 = ((unsigned int)f32_bf16_rtne(v.w) << 16) | f32_bf16_rtne(v.z);
    return make_uint2(u0, u1);
}
// fp16 x4 pack/unpack (GEMM intermediates)
__device__ __forceinline__ uint2 pkh4(float4 v) {
    __half2 h0 = __floats2half2_rn(v.x, v.y);
    __half2 h1 = __floats2half2_rn(v.z, v.w);
    uint2 r;
    r.x = *(unsigned int*)&h0;
    r.y = *(unsigned int*)&h1;
    return r;
}
__device__ __forceinline__ float4 uph4(uint2 p) {
    __half2 h0 = *(__half2*)&p.x;
    __half2 h1 = *(__half2*)&p.y;
    float2 f0 = __half22float2(h0), f1 = __half22float2(h1);
    return make_float4(f0.x, f0.y, f1.x, f1.y);
}

// ---------------- init: zero bucket cursors + stats ----------------
__global__ void init_zero(int* gcur, float* st) {
    int idx = blockIdx.x * 256 + threadIdx.x;
    if (idx < NBUK * 16) gcur[idx] = 0;
    if (blockIdx.x == 0 && threadIdx.x < 128) st[threadIdx.x] = 0.f;
}

// ---------------- normalization stats ----------------
__global__ __launch_bounds__(256) void col_sums(const float* __restrict__ x, float* __restrict__ st) {
    int c = threadIdx.x & 63;
    size_t i = (size_t)blockIdx.x * 256 + threadIdx.x;
    size_t stride = (size_t)gridDim.x * 256;
    float s = 0.f, q = 0.f;
    for (size_t e = i; e < (size_t)NN * 64; e += stride) {
        float v = x[e]; s += v; q = fmaf(v, v, q);
    }
    __shared__ float ls[128];
    if (threadIdx.x < 128) ls[threadIdx.x] = 0.f;
    __syncthreads();
    atomicAdd(&ls[c], s); atomicAdd(&ls[64 + c], q);
    __syncthreads();
    if (threadIdx.x < 128) atomicAdd(&st[threadIdx.x], ls[threadIdx.x]);
}

__global__ void finalize_stats(float* st) {
    int c = threadIdx.x;
    if (c < 64) {
        float s = st[c], q = st[64 + c];
        float mean = s / (float)NN;
        float var = (q - s * s / (float)NN) / (float)(NN - 1);
        st[128 + c] = mean;
        st[192 + c] = rsqrtf(fmaxf(var, 1e-20f));
    }
}

// ---------------- xnd = bf16( dis[n] * normalize(x[n]) ) ----------------
__global__ __launch_bounds__(256) void xnd_kernel(const float* __restrict__ x, const float* __restrict__ st,
                                                  const float* __restrict__ dis, uint2* __restrict__ xnd) {
    size_t i = (size_t)blockIdx.x * 256 + threadIdx.x;   // float4 index
    int n = (int)(i >> 4), q = (int)(i & 15);
    float4 v = ((const float4*)x)[i];
    float4 mean4 = ((const float4*)(st + 128))[q];
    float4 istd4 = ((const float4*)(st + 192))[q];
    float dn = dis[n];
    v.x = (v.x - mean4.x) * istd4.x * dn;
    v.y = (v.y - mean4.y) * istd4.y * dn;
    v.z = (v.z - mean4.z) * istd4.z * dn;
    v.w = (v.w - mean4.w) * istd4.w * dn;
    xnd[i] = pk4(v);
}

// ---------------- pass 1: coarse bucket partition, LDS-staged coalesced writes ----------------
__global__ __launch_bounds__(PTHR) void part_kernel(const int* __restrict__ ei, const float* __restrict__ ea,
                                                    int* __restrict__ gcur, int2* __restrict__ ent2) {
    __shared__ int lhist[NBUK];        // counts, then reused as scatter cursors
    __shared__ int lofs[NBUK];         // block-local exclusive offsets
    __shared__ int lbase[NBUK];        // global within-bucket base (from gcur)
    __shared__ int scn[PTHR];          // scan workspace
    __shared__ int2 stage[PCHUNK];     // 16 KB bucket-sorted staging
    __shared__ int  gdst[PCHUNK];      // 8 KB absolute destinations (-1 = drop)
    const int tid = threadIdx.x;
    const int e0 = blockIdx.x * PCHUNK;
    for (int i = tid; i < NBUK; i += PTHR) lhist[i] = 0;
    __syncthreads();
    int   dv[EPT]; int sv[EPT]; float wvv[EPT];
    #pragma unroll
    for (int i = 0; i < EPT; ++i) {
        int e = e0 + i * PTHR + tid;
        dv[i]  = ei[EE + e];
        sv[i]  = ei[e];
        wvv[i] = fabsf(ea[2 * (size_t)e]);
        atomicAdd(&lhist[dv[i] >> 8], 1);
    }
    __syncthreads();
    // exclusive prefix over bucket counts (Hillis-Steele over PTHR lanes)
    scn[tid] = (tid < NBUK) ? lhist[tid] : 0;
    __syncthreads();
    for (int d = 1; d < PTHR; d <<= 1) {
        int t = (tid >= d) ? scn[tid - d] : 0;
        __syncthreads();
        scn[tid] += t;
        __syncthreads();
    }
    if (tid < NBUK) {
        lofs[tid]  = scn[tid] - lhist[tid];                  // exclusive
        lbase[tid] = atomicAdd(&gcur[tid * 16], lhist[tid]); // reserve global run
        lhist[tid] = 0;                                      // reuse as cursor
    }
    __syncthreads();
    // scatter into bucket-sorted LDS staging + precompute global destination
    #pragma unroll
    for (int i = 0; i < EPT; ++i) {
        int d = dv[i];
        int b = d >> 8;
        int li = atomicAdd(&lhist[b], 1);
        int pos = lofs[b] + li;
        stage[pos] = make_int2(sv[i] | ((d & 255) << 24), __float_as_int(wvv[i]));
        int gp_ = lbase[b] + li;
        gdst[pos] = (gp_ < BCAP) ? (b * BCAP + gp_) : -1;
    }
    __syncthreads();
    // write out: consecutive lanes cover consecutive addresses within segments
    for (int i = tid; i < PCHUNK; i += PTHR) {
        int g = gdst[i];
        if (g >= 0) ent2[g] = stage[i];
    }
}

// ---------------- pass 2: per-bucket counting sort in LDS + rng + dis ----------------
// v3: register-cache the bucket's entries across phases (part_kernel's proven
// pattern) — eliminates the second 26 MB ent2 read pass; coalesced write-out.
__global__ __launch_bounds__(256) void bucket_csr(const int2* __restrict__ ent2, const int* __restrict__ gcur,
                                                  int2* __restrict__ ent, int2* __restrict__ rng,
                                                  float* __restrict__ dis) {
    __shared__ int nhist[256];
    __shared__ int scn[256];
    __shared__ float wsum[256];
    __shared__ int pcur[256];
    __shared__ int2 sorted[BCAP];   // 40 KB
    const int tid = threadIdx.x;
    const int b = blockIdx.x;
    const int base = b * BCAP;
    int cnt = gcur[b * 16];
    if (cnt > BCAP) cnt = BCAP;
    nhist[tid] = 0;
    wsum[tid] = 0.f;
    __syncthreads();
    int   meta[EPB]; float wv_[EPB];
    #pragma unroll
    for (int i = 0; i < EPB; ++i) {
        int e = tid + i * 256;
        if (e < cnt) {
            int2 en = ent2[base + e];
            meta[i] = en.x;
            wv_[i]  = __int_as_float(en.y);
            int dl = ((unsigned)en.x) >> 24;
            atomicAdd(&nhist[dl], 1);
            atomicAdd(&wsum[dl], wv_[i]);
        } else {
            meta[i] = 0; wv_[i] = 0.f;
        }
    }
    __syncthreads();
    int c = nhist[tid];
    scn[tid] = c;
    __syncthreads();
    for (int d = 1; d < 256; d <<= 1) {
        int t = (tid >= d) ? scn[tid - d] : 0;
        __syncthreads();
        scn[tid] += t;
        __syncthreads();
    }
    int ps = scn[tid] - c;                       // exclusive prefix within bucket
    rng[b * 256 + tid] = make_int2(base + ps, base + ps + c);
    dis[b * 256 + tid] = rsqrtf(1.f + wsum[tid]); // self-loop weight 1 folded in
    pcur[tid] = ps;
    __syncthreads();
    #pragma unroll
    for (int i = 0; i < EPB; ++i) {
        int e = tid + i * 256;
        if (e < cnt) {
            int dl = ((unsigned)meta[i]) >> 24;
            int local = atomicAdd(&pcur[dl], 1);
            sorted[local] = make_int2(meta[i] & 0xFFFFFF, __float_as_int(wv_[i]));
        }
    }
    __syncthreads();
    // coalesced write-out
    for (int e = tid; e < cnt; e += 256)
        ent[base + e] = sorted[e];
}

// ---------------- fused MFMA GEMM 1+2: h2 = bf16(dis*(relu(a1@W1 + b1)@W2)) ----------------
#define G1_LD 72
#define G2_LD 104
__global__ __launch_bounds__(256) void fused_gemm12(
    const unsigned short* __restrict__ A, const float* __restrict__ W1,
    const float* __restrict__ b1v, const float* __restrict__ W2,
    const float* __restrict__ dscale, unsigned short* __restrict__ h2out)
{
    __shared__ __align__(16) _Float16 As[64 * G1_LD];    // a1 rows f16 (9.2 KB)
    __shared__ __align__(16) _Float16 G1s[64 * G2_LD];   // relu(g1+b1) f16 (13.3 KB)
    __shared__ float ds[64];
    const int tid  = threadIdx.x;
    const int lane = tid & 63;
    const int wv   = tid >> 6;          // wave 0..3
    const int n15  = lane & 15;
    const int quad = lane >> 4;
    const size_t row0 = (size_t)blockIdx.x * 64;

    if (tid < 64) ds[tid] = dscale[row0 + tid];

    // ---- W1 frags: ctiles {wv, wv+4 if wv<2} covering 0..5; hi + lo*2048 f16 ----
    const int nt1 = (wv < 2) ? 2 : 1;
    f16x8 w1h[2][2], w1l[2][2];
    float b1c[2] = {0.f, 0.f};
    #pragma unroll
    for (int t = 0; t < 2; ++t) {
        if (t < nt1) {
            const int col = (wv + 4 * t) * 16 + n15;
            b1c[t] = b1v[col];
            #pragma unroll
            for (int kc = 0; kc < 2; ++kc) {
                #pragma unroll
                for (int j = 0; j < 8; ++j) {
                    float w = W1[(size_t)(kc * 32 + quad * 8 + j) * 96 + col];
                    _Float16 h = (_Float16)w;
                    w1h[t][kc][j] = h;
                    w1l[t][kc][j] = (_Float16)((w - (float)h) * 2048.f);
                }
            }
        }
    }
    // ---- W2 frags: ctile wv, col = wv*16+n15, 3 k-chunks ----
    f16x8 w2h[3], w2l[3];
    {
        const int col = wv * 16 + n15;
        #pragma unroll
        for (int kc = 0; kc < 3; ++kc) {
            #pragma unroll
            for (int j = 0; j < 8; ++j) {
                float w = W2[(size_t)(kc * 32 + quad * 8 + j) * 64 + col];
                _Float16 h = (_Float16)w;
                w2h[kc][j] = h;
                w2l[kc][j] = (_Float16)((w - (float)h) * 2048.f);
            }
        }
    }

    // ---- stage a1 rows (already fp16): coalesced uint2 copy ----
    for (int i = tid; i < 64 * 16; i += 256) {
        int r = i >> 4, c4 = i & 15;
        uint2 p = *(const uint2*)(A + (row0 + r) * 64 + c4 * 4);
        *(uint2*)(As + r * G1_LD + c4 * 4) = p;
    }
    __syncthreads();

    // ---- phase B: g1 = a1 @ W1, relu(g1+b1) -> G1s f16 ----
    {
        f32x4 acc1[2][4], accl1[2][4];
        #pragma unroll
        for (int t = 0; t < 2; ++t)
            #pragma unroll
            for (int rt = 0; rt < 4; ++rt) {
                acc1[t][rt]  = (f32x4){0.f, 0.f, 0.f, 0.f};
                accl1[t][rt] = (f32x4){0.f, 0.f, 0.f, 0.f};
            }
        #pragma unroll
        for (int kc = 0; kc < 2; ++kc) {
            #pragma unroll
            for (int rt = 0; rt < 4; ++rt) {
                f16x8 a = *(const f16x8*)(As + (rt * 16 + n15) * G1_LD + kc * 32 + quad * 8);
                acc1[0][rt]  = __builtin_amdgcn_mfma_f32_16x16x32_f16(a, w1h[0][kc], acc1[0][rt],  0, 0, 0);
                accl1[0][rt] = __builtin_amdgcn_mfma_f32_16x16x32_f16(a, w1l[0][kc], accl1[0][rt], 0, 0, 0);
                if (nt1 == 2) {
                    acc1[1][rt]  = __builtin_amdgcn_mfma_f32_16x16x32_f16(a, w1h[1][kc], acc1[1][rt],  0, 0, 0);
                    accl1[1][rt] = __builtin_amdgcn_mfma_f32_16x16x32_f16(a, w1l[1][kc], accl1[1][rt], 0, 0, 0);
                }
            }
        }
        #pragma unroll
        for (int t = 0; t < 2; ++t) {
            if (t < nt1) {
                const int col = (wv + 4 * t) * 16 + n15;
                #pragma unroll
                for (int rt = 0; rt < 4; ++rt) {
                    f32x4 c = acc1[t][rt] + accl1[t][rt] * (1.f / 2048.f);
                    #pragma unroll
                    for (int r = 0; r < 4; ++r) {
                        int row = rt * 16 + quad * 4 + r;
                        G1s[row * G2_LD + col] = (_Float16)fmaxf(c[r] + b1c[t], 0.f);
                    }
                }
            }
        }
    }
    __syncthreads();

    // ---- phase C: h2 = bf16(dis * (relu_g1 @ W2)) ----
    {
        f32x4 acc[4], accl[4];
        #pragma unroll
        for (int rt = 0; rt < 4; ++rt) {
            acc[rt]  = (f32x4){0.f, 0.f, 0.f, 0.f};
            accl[rt] = (f32x4){0.f, 0.f, 0.f, 0.f};
        }
        #pragma unroll
        for (int kc = 0; kc < 3; ++kc) {
            #pragma unroll
            for (int rt = 0; rt < 4; ++rt) {
                f16x8 a = *(const f16x8*)(G1s + (rt * 16 + n15) * G2_LD + kc * 32 + quad * 8);
                acc[rt]  = __builtin_amdgcn_mfma_f32_16x16x32_f16(a, w2h[kc], acc[rt],  0, 0, 0);
                accl[rt] = __builtin_amdgcn_mfma_f32_16x16x32_f16(a, w2l[kc], accl[rt], 0, 0, 0);
            }
        }
        const int col = wv * 16 + n15;
        #pragma unroll
        for (int rt = 0; rt < 4; ++rt) {
            f32x4 c = acc[rt] + accl[rt] * (1.f / 2048.f);
            #pragma unroll
            for (int r = 0; r < 4; ++r) {
                int row = rt * 16 + quad * 4 + r;
                float v = c[r] * ds[row];
                h2out[(row0 + row) * 64 + col] = f32_bf16_rtne(v);
            }
        }
    }
}

// ---------------- GCN aggregation: gather over packed CSR (rng int2 ranges) ----------------
template<int C4>
__global__ __launch_bounds__(256) void gcn_gather(const uint2* __restrict__ h, const int2* __restrict__ rng,
                                                  const int2* __restrict__ ent, const float* __restrict__ dis,
                                                  unsigned short* __restrict__ g) {
    unsigned int idx = blockIdx.x * 256 + threadIdx.x;
    unsigned int n = idx / C4, q = idx % C4;
    float4 acc = unp4(h[(size_t)n * C4 + q]);
    int2 r = rng[n];
    int e = r.x;
    for (; e + 8 <= r.y; e += 8) {
        int2 en0 = ent[e],     en1 = ent[e + 1], en2 = ent[e + 2], en3 = ent[e + 3];
        int2 en4 = ent[e + 4], en5 = ent[e + 5], en6 = ent[e + 6], en7 = ent[e + 7];
        uint2 v0 = h[(size_t)en0.x * C4 + q];
        uint2 v1 = h[(size_t)en1.x * C4 + q];
        uint2 v2 = h[(size_t)en2.x * C4 + q];
        uint2 v3 = h[(size_t)en3.x * C4 + q];
        uint2 v4 = h[(size_t)en4.x * C4 + q];
        uint2 v5 = h[(size_t)en5.x * C4 + q];
        uint2 v6 = h[(size_t)en6.x * C4 + q];
        uint2 v7 = h[(size_t)en7.x * C4 + q];
        fma4(acc, __int_as_float(en0.y), unp4(v0));
        fma4(acc, __int_as_float(en1.y), unp4(v1));
        fma4(acc, __int_as_float(en2.y), unp4(v2));
        fma4(acc, __int_as_float(en3.y), unp4(v3));
        fma4(acc, __int_as_float(en4.y), unp4(v4));
        fma4(acc, __int_as_float(en5.y), unp4(v5));
        fma4(acc, __int_as_float(en6.y), unp4(v6));
        fma4(acc, __int_as_float(en7.y), unp4(v7));
    }
    for (; e + 4 <= r.y; e += 4) {
        int2 en0 = ent[e], en1 = ent[e + 1], en2 = ent[e + 2], en3 = ent[e + 3];
        uint2 v0 = h[(size_t)en0.x * C4 + q];
        uint2 v1 = h[(size_t)en1.x * C4 + q];
        uint2 v2 = h[(size_t)en2.x * C4 + q];
        uint2 v3 = h[(size_t)en3.x * C4 + q];
        fma4(acc, __int_as_float(en0.y), unp4(v0));
        fma4(acc, __int_as_float(en1.y), unp4(v1));
        fma4(acc, __int_as_float(en2.y), unp4(v2));
        fma4(acc, __int_as_float(en3.y), unp4(v3));
    }
    for (; e < r.y; ++e) {
        int2 en = ent[e];
        uint2 v = h[(size_t)en.x * C4 + q];
        fma4(acc, __int_as_float(en.y), unp4(v));
    }
    float dn = dis[n];
    acc.x *= dn; acc.y *= dn; acc.z *= dn; acc.w *= dn;
    *(uint2*)(g + (size_t)n * (C4 * 4) + q * 4) = pkh4(acc);
}

// ---------------- fused LSTM: x-path GEMM + recurrence, all MFMA (f16, split planes) ----------------
// v3: 8 waves (512 thr), 2 gate-tiles per wave. Best measured variant (~41us,
// 88 VGPR). Do NOT fuse epilogues in (R12: VGPR 88->120 slowed loop 46->71us).
#define XP_LD 72   // xpack seq-row stride (halves): 4*(n15+quad) bank spread
#define HP_LD2 72  // h plane row stride (halves)
#define GP_LD 258  // gp row stride (floats): store banks 8q+2r+n15 = 2/bank floor

__global__ __launch_bounds__(512, 1) void lstm_kernel(
    const __half* __restrict__ g2, const float* __restrict__ cb2,
    const float* __restrict__ whh, const float* __restrict__ wih,
    const float* __restrict__ bih, const float* __restrict__ bhh,
    float* __restrict__ hlast)
{
    __shared__ __align__(16) _Float16 xpack[32 * 16 * XP_LD];  // 73.7 KB
    __shared__ __align__(16) _Float16 hhi[16 * HP_LD2];        // 2.25 KB
    __shared__ __align__(16) _Float16 hlo[16 * HP_LD2];        // 2.25 KB
    __shared__ float gp[16 * GP_LD];                           // 16.1 KB
    const int tid  = threadIdx.x;       // 0..511
    const int lane = tid & 63;
    const int wv   = tid >> 6;          // wave 0..7
    const int n15  = lane & 15;         // A: seq m / B: gate-in-tile n
    const int quad = lane >> 4;         // k sub-block
    const int ja   = lane;              // activation hidden unit 0..63

    // ---- loop-invariant B-frags for 2 gate tiles: gate = (wv+8*tl)*16+n15 ----
    f16x8 whh_h[2][2], whh_l[2][2], wih_h[2][2], wih_l[2][2];  // [tile][kc]
    #pragma unroll
    for (int tl = 0; tl < 2; ++tl) {
        const int gate = (wv + 8 * tl) * 16 + n15;
        const float* wp = whh + (size_t)gate * 64 + quad * 8;
        const float* xp = wih + (size_t)gate * 64 + quad * 8;
        #pragma unroll
        for (int kc = 0; kc < 2; ++kc) {
            #pragma unroll
            for (int j = 0; j < 8; ++j) {
                float w = wp[kc * 32 + j];
                _Float16 h = (_Float16)w;
                whh_h[tl][kc][j] = h;
                whh_l[tl][kc][j] = (_Float16)((w - (float)h) * 2048.f);
                float v = xp[kc * 32 + j];
                _Float16 g = (_Float16)v;
                wih_h[tl][kc][j] = g;
                wih_l[tl][kc][j] = (_Float16)((v - (float)g) * 2048.f);
            }
        }
    }

    // ---- activation-phase gate biases (b_ih + b_hh), f32 (depend on ja only) ----
    const float bi_i = bih[ja]        + bhh[ja];
    const float bi_f = bih[64 + ja]   + bhh[64 + ja];
    const float bi_g = bih[128 + ja]  + bhh[128 + ja];
    const float bi_o = bih[192 + ja]  + bhh[192 + ja];

    // ---- prologue: stage xr = relu(g2 + conv2_b) into xpack, fully coalesced ----
    {
        const int s0 = blockIdx.x * 16;          // 400 % 16 == 0: block never straddles b_
        const int b_ = s0 / NODESC;
        const int node0 = s0 - b_ * NODESC;
        const int r  = (tid >> 4) & 15;          // seq row (fixed per thread)
        const int c4 = tid & 15;                 // 4-half group within row
        const int t0 = tid >> 8;                 // 0..1; t = t0 + 2*i
        float4 bias4 = *(const float4*)(cb2 + c4 * 4);
        _Float16* dst = xpack + r * XP_LD + c4 * 4;
        const __half* src = g2 + ((size_t)(b_ * TT + t0) * NODESC + node0 + r) * 64 + c4 * 4;
        #pragma unroll
        for (int i = 0; i < 16; ++i) {
            uint2 p = *(const uint2*)(src + (size_t)i * 2 * NODESC * 64);
            float4 v = uph4(p);
            v.x = fmaxf(v.x + bias4.x, 0.f);
            v.y = fmaxf(v.y + bias4.y, 0.f);
            v.z = fmaxf(v.z + bias4.z, 0.f);
            v.w = fmaxf(v.w + bias4.w, 0.f);
            *(uint2*)(dst + (size_t)(t0 + i * 2) * (16 * XP_LD)) = pkh4(v);
        }
    }

    // ---- init h = 0 ----
    for (int i = tid; i < 16 * HP_LD2; i += 512) { hhi[i] = (_Float16)0.f; hlo[i] = (_Float16)0.f; }
    float cA_reg = 0.f, hA = 0.f;   // state for (qa = wv, ja)
    float cB_reg = 0.f, hB = 0.f;   // state for (qa = wv+8, ja)
    __syncthreads();

    const int xbase = n15 * XP_LD + quad * 8;    // halves, 16B-aligned
    const int hbase = n15 * HP_LD2 + quad * 8;

    for (int t = 0; t < TT; ++t) {
        // ---- dot phase: 6 A-frag reads shared by 2 tiles, 20 MFMAs, 6 chains ----
        f32x4 cmA  = {0.f,0.f,0.f,0.f}, clA0 = {0.f,0.f,0.f,0.f}, clA1 = {0.f,0.f,0.f,0.f};
        f32x4 cmB  = {0.f,0.f,0.f,0.f}, clB0 = {0.f,0.f,0.f,0.f}, clB1 = {0.f,0.f,0.f,0.f};
        const _Float16* xrow = xpack + (size_t)t * (16 * XP_LD);
        {
            f16x8 ax0 = *(const f16x8*)(xrow + xbase);
            f16x8 ah0 = *(const f16x8*)(hhi + hbase);
            f16x8 al0 = *(const f16x8*)(hlo + hbase);
            f16x8 ax1 = *(const f16x8*)(xrow + xbase + 32);
            f16x8 ah1 = *(const f16x8*)(hhi + hbase + 32);
            f16x8 al1 = *(const f16x8*)(hlo + hbase + 32);
            cmA  = __builtin_amdgcn_mfma_f32_16x16x32_f16(ax0, wih_h[0][0], cmA,  0, 0, 0);
            cmB  = __builtin_amdgcn_mfma_f32_16x16x32_f16(ax0, wih_h[1][0], cmB,  0, 0, 0);
            clA0 = __builtin_amdgcn_mfma_f32_16x16x32_f16(ax0, wih_l[0][0], clA0, 0, 0, 0);
            clB0 = __builtin_amdgcn_mfma_f32_16x16x32_f16(ax0, wih_l[1][0], clB0, 0, 0, 0);
            clA1 = __builtin_amdgcn_mfma_f32_16x16x32_f16(ax1, wih_l[0][1], clA1, 0, 0, 0);
            clB1 = __builtin_amdgcn_mfma_f32_16x16x32_f16(ax1, wih_l[1][1], clB1, 0, 0, 0);
            cmA  = __builtin_amdgcn_mfma_f32_16x16x32_f16(ah0, whh_h[0][0], cmA,  0, 0, 0);
            cmB  = __builtin_amdgcn_mfma_f32_16x16x32_f16(ah0, whh_h[1][0], cmB,  0, 0, 0);
            clA0 = __builtin_amdgcn_mfma_f32_16x16x32_f16(al0, whh_h[0][0], clA0, 0, 0, 0);
            clB0 = __builtin_amdgcn_mfma_f32_16x16x32_f16(al0, whh_h[1][0], clB0, 0, 0, 0);
            clA1 = __builtin_amdgcn_mfma_f32_16x16x32_f16(al1, whh_h[0][1], clA1, 0, 0, 0);
            clB1 = __builtin_amdgcn_mfma_f32_16x16x32_f16(al1, whh_h[1][1], clB1, 0, 0, 0);
            cmA  = __builtin_amdgcn_mfma_f32_16x16x32_f16(ax1, wih_h[0][1], cmA,  0, 0, 0);
            cmB  = __builtin_amdgcn_mfma_f32_16x16x32_f16(ax1, wih_h[1][1], cmB,  0, 0, 0);
            clA0 = __builtin_amdgcn_mfma_f32_16x16x32_f16(ah0, whh_l[0][0], clA0, 0, 0, 0);
            clB0 = __builtin_amdgcn_mfma_f32_16x16x32_f16(ah0, whh_l[1][0], clB0, 0, 0, 0);
            clA1 = __builtin_amdgcn_mfma_f32_16x16x32_f16(ah1, whh_l[0][1], clA1, 0, 0, 0);
            clB1 = __builtin_amdgcn_mfma_f32_16x16x32_f16(ah1, whh_l[1][1], clB1, 0, 0, 0);
            cmA  = __builtin_amdgcn_mfma_f32_16x16x32_f16(ah1, whh_h[0][1], cmA,  0, 0, 0);
            cmB  = __builtin_amdgcn_mfma_f32_16x16x32_f16(ah1, whh_h[1][1], cmB,  0, 0, 0);
        }
        f32x4 cA = cmA + (clA0 + clA1) * (1.f / 2048.f);
        f32x4 cB = cmB + (clB0 + clB1) * (1.f / 2048.f);
        // C: lane holds seqs m = quad*4+r; columns wv*16+n15 and (wv+8)*16+n15
        #pragma unroll
        for (int r = 0; r < 4; ++r) {
            gp[(quad * 4 + r) * GP_LD + wv * 16 + n15]       = cA[r];
            gp[(quad * 4 + r) * GP_LD + (wv + 8) * 16 + n15] = cB[r];
        }
        __syncthreads();

        // ---- activation phase: thread handles (wv, ja) and (wv+8, ja) ----
        {
            const int qa = wv;
            float gi = gp[qa * GP_LD + ja]        + bi_i;
            float gf = gp[qa * GP_LD + 64 + ja]   + bi_f;
            float gg = gp[qa * GP_LD + 128 + ja]  + bi_g;
            float go = gp[qa * GP_LD + 192 + ja]  + bi_o;
            cA_reg = sigm_f(gf) * cA_reg + sigm_f(gi) * tanh_f(gg);
            hA = sigm_f(go) * tanh_f(cA_reg);
            _Float16 hh = (_Float16)hA;
            hhi[qa * HP_LD2 + ja] = hh;
            hlo[qa * HP_LD2 + ja] = (_Float16)((hA - (float)hh) * 2048.f);
        }
        {
            const int qa = wv + 8;
            float gi = gp[qa * GP_LD + ja]        + bi_i;
            float gf = gp[qa * GP_LD + 64 + ja]   + bi_f;
            float gg = gp[qa * GP_LD + 128 + ja]  + bi_g;
            float go = gp[qa * GP_LD + 192 + ja]  + bi_o;
            cB_reg = sigm_f(gf) * cB_reg + sigm_f(gi) * tanh_f(gg);
            hB = sigm_f(go) * tanh_f(cB_reg);
            _Float16 hh = (_Float16)hB;
            hhi[qa * HP_LD2 + ja] = hh;
            hlo[qa * HP_LD2 + ja] = (_Float16)((hB - (float)hh) * 2048.f);
        }
        __syncthreads();
    }
    hlast[((size_t)blockIdx.x * 16 + wv) * 64 + ja]     = hA;
    hlast[((size_t)blockIdx.x * 16 + wv + 8) * 64 + ja] = hB;
}

// ---------------- FC head + softmax ----------------
__global__ __launch_bounds__(128) void head_kernel(const float* __restrict__ hl,
                                                   const float* __restrict__ w1, const float* __restrict__ b1,
                                                   const float* __restrict__ w2, const float* __restrict__ b2,
                                                   float* __restrict__ out) {
    __shared__ float hrow[64];
    __shared__ float a1[128];
    __shared__ float lg[3];
    int s = blockIdx.x, tid = threadIdx.x;
    if (tid < 64) hrow[tid] = hl[(size_t)s * 64 + tid];
    __syncthreads();
    {
        const float4* wr = (const float4*)(w1 + (size_t)tid * 64);
        const float4* hq = (const float4*)hrow;
        float4 acc = make_float4(0.f, 0.f, 0.f, 0.f);
        #pragma unroll
        for (int k = 0; k < 16; ++k) {
            float4 wv = wr[k]; float4 hv = hq[k];
            acc.x = fmaf(wv.x, hv.x, acc.x); acc.y = fmaf(wv.y, hv.y, acc.y);
            acc.z = fmaf(wv.z, hv.z, acc.z); acc.w = fmaf(wv.w, hv.w, acc.w);
        }
        a1[tid] = fmaxf((acc.x + acc.y) + (acc.z + acc.w) + b1[tid], 0.f);
    }
    __syncthreads();
    if (tid < 3) {
        const float4* wr = (const float4*)(w2 + (size_t)tid * 128);
        const float4* aq = (const float4*)a1;
        float4 acc = make_float4(0.f, 0.f, 0.f, 0.f);
        #pragma unroll
        for (int k = 0; k < 32; ++k) {
            float4 wv = wr[k]; float4 av = aq[k];
            acc.x = fmaf(wv.x, av.x, acc.x); acc.y = fmaf(wv.y, av.y, acc.y);
            acc.z = fmaf(wv.z, av.z, acc.z); acc.w = fmaf(wv.w, av.w, acc.w);
        }
        lg[tid] = (acc.x + acc.y) + (acc.z + acc.w) + b2[tid];
    }
    __syncthreads();
    if (tid == 0) {
        float m = fmaxf(lg[0], fmaxf(lg[1], lg[2]));
        float e0 = __expf(lg[0] - m), e1 = __expf(lg[1] - m), e2 = __expf(lg[2] - m);
        float inv = 1.f / (e0 + e1 + e2);
        out[(size_t)s * 3 + 0] = e0 * inv;
        out[(size_t)s * 3 + 1] = e1 * inv;
        out[(size_t)s * 3 + 2] = e2 * inv;
    }
}

extern "C" void kernel_launch(void* const* d_in, const int* in_sizes, int n_in,
                              void* d_out, int out_size, void* d_ws, size_t ws_size,
                              hipStream_t stream) {
    (void)in_sizes; (void)n_in; (void)out_size; (void)ws_size;
    const float* x        = (const float*)d_in[0];
    const float* ea       = (const float*)d_in[1];
    const float* conv1_w  = (const float*)d_in[2];
    const float* conv1_b  = (const float*)d_in[3];
    const float* conv2_w  = (const float*)d_in[4];
    const float* conv2_b  = (const float*)d_in[5];
    const float* w_ih     = (const float*)d_in[6];
    const float* w_hh     = (const float*)d_in[7];
    const float* b_ih     = (const float*)d_in[8];
    const float* b_hh     = (const float*)d_in[9];
    const float* fc1_w    = (const float*)d_in[10];
    const float* fc1_b    = (const float*)d_in[11];
    const float* fc2_w    = (const float*)d_in[12];
    const float* fc2_b    = (const float*)d_in[13];
    const int*   ei       = (const int*)d_in[14];
    float* out = (float*)d_out;

    float* W    = (float*)d_ws;
    int2*  ent  = (int2*)(W + OFF_ENT);
    unsigned short* a1h = (unsigned short*)(W + OFF_A1);   // fp16 a1 rows
    int2*  ent2 = (int2*)(W + OFF_ENT2);
    uint2* xnd  = (uint2*)(W + OFF_ENT2);  // bf16 rows; reuses dead csr staging
    float* h2   = W + OFF_H2;              // bf16 rows; overwrites dead xnd (sequentially safe)
    unsigned short* g2h = (unsigned short*)(W + OFF_G2);   // fp16 rows
    int*   gcur = (int*)(W + OFF_GCUR);
    float* dis  = W + OFF_DIS;
    int2*  rng  = (int2*)(W + OFF_RNG);
    float* hl   = W + OFF_HL;
    float* st   = W + OFF_ST;

    // init + normalization stats
    init_zero<<<26, 256, 0, stream>>>(gcur, st);
    col_sums<<<1024, 256, 0, stream>>>(x, st);
    finalize_stats<<<1, 64, 0, stream>>>(st);

    // dest-sorted CSR via two-pass counting sort (coalesced writes, no global float atomics)
    part_kernel<<<NPART, PTHR, 0, stream>>>(ei, ea, gcur, ent2);
    bucket_csr<<<NBUK, 256, 0, stream>>>(ent2, gcur, ent, rng, dis);

    // pre-scaled bf16 node features: xnd = bf16(dis * normalize(x))
    xnd_kernel<<<NN * 16 / 256, 256, 0, stream>>>(x, st, dis, xnd);

    // GCN layer 1 aggregation (full parallelism): a1 = S·xnd (fp16 out)
    gcn_gather<16><<<NN * 16 / 256, 256, 0, stream>>>(xnd, rng, ent, dis, a1h);

    // fused GEMM 1+2: h2 = bf16(dis*(relu(a1@W1 + b1)@W2)) — saves g1 round-trip
    fused_gemm12<<<NN / 64, 256, 0, stream>>>(a1h, conv1_w, conv1_b, conv2_w, dis,
                                              (unsigned short*)h2);

    // GCN layer 2 aggregation: g2 = S·h2 (fp16 out)
    gcn_gather<16><<<NN * 16 / 256, 256, 0, stream>>>((const uint2*)h2, rng, ent, dis, g2h);

    // fused LSTM v3: x-path GEMM + recurrence, all MFMA f16
    lstm_kernel<<<SS / 16, 512, 0, stream>>>((const __half*)g2h, conv2_b, w_hh, w_ih,
                                             b_ih, b_hh, hl);

    // FC head + softmax
    head_kernel<<<SS, 128, 0, stream>>>(hl, fc1_w, fc1_b, fc2_w, fc2_b, out);
}

// Round 15
// 321.969 us; speedup vs baseline: 1.0862x; 1.0393x over previous
//
#include <hip/hip_runtime.h>
#include <hip/hip_bf16.h>
#include <hip/hip_fp16.h>

#define NN 102400      // B*T*NODES
#define DD 64
#define EE 1638400
#define L1C 96
#define L2C 64
#define TT 32
#define NODESC 400
#define BB 8
#define SS 3200        // B*NODES
#define G4 256         // 4*D

#define NBUK 400       // coarse buckets (node >> 8), NN = 400*256 exactly
#define BCAP 5120      // slots per bucket (mean 4096, sd 64 -> +16 sigma)
#define PCHUNK 2048    // 800 blocks x 512 thr
#define NPART (EE / PCHUNK)   // 800
#define PTHR 512
#define EPT (PCHUNK / PTHR)   // 4 edges per thread
#define EPB (BCAP / 256)      // 20 entries per thread in bucket_csr
#define NCOLB 512             // col-sum blocks appended to the part grid

// ---------------- workspace layout (floats) ----------------
#define OFF_ENT  ((size_t)0)          // NBUK*BCAP int2 = 4,096,000 floats
#define OFF_A1   ((size_t)4096000)    // NN*64 fp16 a1 rows
#define OFF_ENT2 ((size_t)26214400)   // csr staging; then xnd bf16; then h2 bf16
#define OFF_H2   ((size_t)26214400)   // NN*64 bf16 (overwrites dead xnd)
#define OFF_G2   ((size_t)32768000)   // NN*64 fp16
#define OFF_GCUR ((size_t)39321600)   // 400 cursors padded x16 ints = 6400
#define OFF_DIS  ((size_t)39328000)   // NN -> ends 39,430,400
#define OFF_RNG  ((size_t)39430400)   // NN int2 -> ends 39,635,200
#define OFF_HL   ((size_t)39635200)   // SS*64 -> ends 39,840,000
#define OFF_ST   ((size_t)39840000)   // 256 -> ends 39,840,256

typedef __attribute__((ext_vector_type(8))) _Float16 f16x8;  // 8 f16 in 4 VGPRs
typedef __attribute__((ext_vector_type(4))) float f32x4;

__device__ __forceinline__ void fma4(float4& a, float s, const float4& w) {
    a.x = fmaf(s, w.x, a.x); a.y = fmaf(s, w.y, a.y);
    a.z = fmaf(s, w.z, a.z); a.w = fmaf(s, w.w, a.w);
}
__device__ __forceinline__ float rcp_f(float x) { return __builtin_amdgcn_rcpf(x); }
__device__ __forceinline__ float sigm_f(float x) {
    x = fminf(fmaxf(x, -30.f), 30.f);
    return rcp_f(1.f + __expf(-x));
}
__device__ __forceinline__ float tanh_f(float x) {
    x = fminf(fmaxf(x, -15.f), 15.f);
    float e = __expf(2.f * x);
    return (e - 1.f) * rcp_f(e + 1.f);
}
__device__ __forceinline__ unsigned short f32_bf16_rtne(float f) {
    unsigned int u = __float_as_uint(f);
    unsigned int r = u + 0x7fffu + ((u >> 16) & 1u);
    return (unsigned short)(r >> 16);
}
__device__ __forceinline__ float bf16_f32(unsigned short h) {
    return __uint_as_float(((unsigned int)h) << 16);
}
// bf16 x4 pack/unpack (gather tables)
__device__ __forceinline__ float4 unp4(uint2 p) {
    float4 v;
    v.x = __uint_as_float(p.x << 16);
    v.y = __uint_as_float(p.x & 0xffff0000u);
    v.z = __uint_as_float(p.y << 16);
    v.w = __uint_as_float(p.y & 0xffff0000u);
    return v;
}
__device__ __forceinline__ uint2 pk4(float4 v) {
    unsigned int u0 = ((unsigned int)f32_bf16_rtne(v.y) << 16) | f32_bf16_rtne(v.x);
    unsigned int u1 = ((unsigned int)f32_bf16_rtne(v.w) << 16) | f32_bf16_rtne(v.z);
    return make_uint2(u0, u1);
}
// fp16 x4 pack/unpack (GEMM intermediates)
__device__ __forceinline__ uint2 pkh4(float4 v) {
    __half2 h0 = __floats2half2_rn(v.x, v.y);
    __half2 h1 = __floats2half2_rn(v.z, v.w);
    uint2 r;
    r.x = *(unsigned int*)&h0;
    r.y = *(unsigned int*)&h1;
    return r;
}
__device__ __forceinline__ float4 uph4(uint2 p) {
    __half2 h0 = *(__half2*)&p.x;
    __half2 h1 = *(__half2*)&p.y;
    float2 f0 = __half22float2(h0), f1 = __half22float2(h1);
    return make_float4(f0.x, f0.y, f1.x, f1.y);
}

// ---------------- init: zero bucket cursors + stats ----------------
__global__ void init_zero(int* gcur, float* st) {
    int idx = blockIdx.x * 256 + threadIdx.x;
    if (idx < NBUK * 16) gcur[idx] = 0;
    if (blockIdx.x == 0 && threadIdx.x < 128) st[threadIdx.x] = 0.f;
}

__global__ void finalize_stats(float* st) {
    int c = threadIdx.x;
    if (c < 64) {
        float s = st[c], q = st[64 + c];
        float mean = s / (float)NN;
        float var = (q - s * s / (float)NN) / (float)(NN - 1);
        st[128 + c] = mean;
        st[192 + c] = rsqrtf(fmaxf(var, 1e-20f));
    }
}

// ---------------- xnd = bf16( dis[n] * normalize(x[n]) ) ----------------
__global__ __launch_bounds__(256) void xnd_kernel(const float* __restrict__ x, const float* __restrict__ st,
                                                  const float* __restrict__ dis, uint2* __restrict__ xnd) {
    size_t i = (size_t)blockIdx.x * 256 + threadIdx.x;   // float4 index
    int n = (int)(i >> 4), q = (int)(i & 15);
    float4 v = ((const float4*)x)[i];
    float4 mean4 = ((const float4*)(st + 128))[q];
    float4 istd4 = ((const float4*)(st + 192))[q];
    float dn = dis[n];
    v.x = (v.x - mean4.x) * istd4.x * dn;
    v.y = (v.y - mean4.y) * istd4.y * dn;
    v.z = (v.z - mean4.z) * istd4.z * dn;
    v.w = (v.w - mean4.w) * istd4.w * dn;
    xnd[i] = pk4(v);
}

// ---------------- merged pass 1 + col_sums (heterogeneous grid) ----------------
// part blocks are latency-bound (26% occ, 12% HBM, VALU idle); col_sums is a
// pure HBM stream. Co-scheduling them in one launch overlaps the stream under
// the partition's idle memory pipe: combined ~= max instead of sum, and one
// launch overhead disappears. blockIdx < NPART -> partition; else col-sums
// (grid-strided, thread-count agnostic). Bodies are byte-identical to R14.
__global__ __launch_bounds__(PTHR) void part_cols(const int* __restrict__ ei, const float* __restrict__ ea,
                                                  int* __restrict__ gcur, int2* __restrict__ ent2,
                                                  const float* __restrict__ x, float* __restrict__ st) {
    __shared__ int lhist[NBUK];        // counts, then reused as scatter cursors
    __shared__ int lofs[NBUK];         // block-local exclusive offsets
    __shared__ int lbase[NBUK];        // global within-bucket base (from gcur)
    __shared__ int scn[PTHR];          // scan workspace
    __shared__ int2 stage[PCHUNK];     // 16 KB bucket-sorted staging
    __shared__ int  gdst[PCHUNK];      // 8 KB absolute destinations (-1 = drop)
    __shared__ float ls[128];          // col-sums reduction
    const int tid = threadIdx.x;

    if (blockIdx.x >= NPART) {
        // ---- col_sums path ----
        const int cb = blockIdx.x - NPART;
        int c = tid & 63;
        size_t i = (size_t)cb * PTHR + tid;
        size_t stride = (size_t)NCOLB * PTHR;
        float s = 0.f, q = 0.f;
        for (size_t e = i; e < (size_t)NN * 64; e += stride) {
            float v = x[e]; s += v; q = fmaf(v, v, q);
        }
        if (tid < 128) ls[tid] = 0.f;
        __syncthreads();
        atomicAdd(&ls[c], s); atomicAdd(&ls[64 + c], q);
        __syncthreads();
        if (tid < 128) atomicAdd(&st[tid], ls[tid]);
        return;
    }

    // ---- partition path ----
    const int e0 = blockIdx.x * PCHUNK;
    for (int i = tid; i < NBUK; i += PTHR) lhist[i] = 0;
    __syncthreads();
    int   dv[EPT]; int sv[EPT]; float wvv[EPT];
    #pragma unroll
    for (int i = 0; i < EPT; ++i) {
        int e = e0 + i * PTHR + tid;
        dv[i]  = ei[EE + e];
        sv[i]  = ei[e];
        wvv[i] = fabsf(ea[2 * (size_t)e]);
        atomicAdd(&lhist[dv[i] >> 8], 1);
    }
    __syncthreads();
    // exclusive prefix over bucket counts (Hillis-Steele over PTHR lanes)
    scn[tid] = (tid < NBUK) ? lhist[tid] : 0;
    __syncthreads();
    for (int d = 1; d < PTHR; d <<= 1) {
        int t = (tid >= d) ? scn[tid - d] : 0;
        __syncthreads();
        scn[tid] += t;
        __syncthreads();
    }
    if (tid < NBUK) {
        lofs[tid]  = scn[tid] - lhist[tid];                  // exclusive
        lbase[tid] = atomicAdd(&gcur[tid * 16], lhist[tid]); // reserve global run
        lhist[tid] = 0;                                      // reuse as cursor
    }
    __syncthreads();
    // scatter into bucket-sorted LDS staging + precompute global destination
    #pragma unroll
    for (int i = 0; i < EPT; ++i) {
        int d = dv[i];
        int b = d >> 8;
        int li = atomicAdd(&lhist[b], 1);
        int pos = lofs[b] + li;
        stage[pos] = make_int2(sv[i] | ((d & 255) << 24), __float_as_int(wvv[i]));
        int gp_ = lbase[b] + li;
        gdst[pos] = (gp_ < BCAP) ? (b * BCAP + gp_) : -1;
    }
    __syncthreads();
    // write out: consecutive lanes cover consecutive addresses within segments
    for (int i = tid; i < PCHUNK; i += PTHR) {
        int g = gdst[i];
        if (g >= 0) ent2[g] = stage[i];
    }
}

// ---------------- pass 2: per-bucket counting sort in LDS + rng + dis ----------------
// v3: register-cache the bucket's entries across phases; coalesced write-out.
__global__ __launch_bounds__(256) void bucket_csr(const int2* __restrict__ ent2, const int* __restrict__ gcur,
                                                  int2* __restrict__ ent, int2* __restrict__ rng,
                                                  float* __restrict__ dis) {
    __shared__ int nhist[256];
    __shared__ int scn[256];
    __shared__ float wsum[256];
    __shared__ int pcur[256];
    __shared__ int2 sorted[BCAP];   // 40 KB
    const int tid = threadIdx.x;
    const int b = blockIdx.x;
    const int base = b * BCAP;
    int cnt = gcur[b * 16];
    if (cnt > BCAP) cnt = BCAP;
    nhist[tid] = 0;
    wsum[tid] = 0.f;
    __syncthreads();
    int   meta[EPB]; float wv_[EPB];
    #pragma unroll
    for (int i = 0; i < EPB; ++i) {
        int e = tid + i * 256;
        if (e < cnt) {
            int2 en = ent2[base + e];
            meta[i] = en.x;
            wv_[i]  = __int_as_float(en.y);
            int dl = ((unsigned)en.x) >> 24;
            atomicAdd(&nhist[dl], 1);
            atomicAdd(&wsum[dl], wv_[i]);
        } else {
            meta[i] = 0; wv_[i] = 0.f;
        }
    }
    __syncthreads();
    int c = nhist[tid];
    scn[tid] = c;
    __syncthreads();
    for (int d = 1; d < 256; d <<= 1) {
        int t = (tid >= d) ? scn[tid - d] : 0;
        __syncthreads();
        scn[tid] += t;
        __syncthreads();
    }
    int ps = scn[tid] - c;                       // exclusive prefix within bucket
    rng[b * 256 + tid] = make_int2(base + ps, base + ps + c);
    dis[b * 256 + tid] = rsqrtf(1.f + wsum[tid]); // self-loop weight 1 folded in
    pcur[tid] = ps;
    __syncthreads();
    #pragma unroll
    for (int i = 0; i < EPB; ++i) {
        int e = tid + i * 256;
        if (e < cnt) {
            int dl = ((unsigned)meta[i]) >> 24;
            int local = atomicAdd(&pcur[dl], 1);
            sorted[local] = make_int2(meta[i] & 0xFFFFFF, __float_as_int(wv_[i]));
        }
    }
    __syncthreads();
    // coalesced write-out
    for (int e = tid; e < cnt; e += 256)
        ent[base + e] = sorted[e];
}

// ---------------- fused MFMA GEMM 1+2: h2 = bf16(dis*(relu(a1@W1 + b1)@W2)) ----------------
#define G1_LD 72
#define G2_LD 104
__global__ __launch_bounds__(256) void fused_gemm12(
    const unsigned short* __restrict__ A, const float* __restrict__ W1,
    const float* __restrict__ b1v, const float* __restrict__ W2,
    const float* __restrict__ dscale, unsigned short* __restrict__ h2out)
{
    __shared__ __align__(16) _Float16 As[64 * G1_LD];    // a1 rows f16 (9.2 KB)
    __shared__ __align__(16) _Float16 G1s[64 * G2_LD];   // relu(g1+b1) f16 (13.3 KB)
    __shared__ float ds[64];
    const int tid  = threadIdx.x;
    const int lane = tid & 63;
    const int wv   = tid >> 6;          // wave 0..3
    const int n15  = lane & 15;
    const int quad = lane >> 4;
    const size_t row0 = (size_t)blockIdx.x * 64;

    if (tid < 64) ds[tid] = dscale[row0 + tid];

    // ---- W1 frags: ctiles {wv, wv+4 if wv<2} covering 0..5; hi + lo*2048 f16 ----
    const int nt1 = (wv < 2) ? 2 : 1;
    f16x8 w1h[2][2], w1l[2][2];
    float b1c[2] = {0.f, 0.f};
    #pragma unroll
    for (int t = 0; t < 2; ++t) {
        if (t < nt1) {
            const int col = (wv + 4 * t) * 16 + n15;
            b1c[t] = b1v[col];
            #pragma unroll
            for (int kc = 0; kc < 2; ++kc) {
                #pragma unroll
                for (int j = 0; j < 8; ++j) {
                    float w = W1[(size_t)(kc * 32 + quad * 8 + j) * 96 + col];
                    _Float16 h = (_Float16)w;
                    w1h[t][kc][j] = h;
                    w1l[t][kc][j] = (_Float16)((w - (float)h) * 2048.f);
                }
            }
        }
    }
    // ---- W2 frags: ctile wv, col = wv*16+n15, 3 k-chunks ----
    f16x8 w2h[3], w2l[3];
    {
        const int col = wv * 16 + n15;
        #pragma unroll
        for (int kc = 0; kc < 3; ++kc) {
            #pragma unroll
            for (int j = 0; j < 8; ++j) {
                float w = W2[(size_t)(kc * 32 + quad * 8 + j) * 64 + col];
                _Float16 h = (_Float16)w;
                w2h[kc][j] = h;
                w2l[kc][j] = (_Float16)((w - (float)h) * 2048.f);
            }
        }
    }

    // ---- stage a1 rows (already fp16): coalesced uint2 copy ----
    for (int i = tid; i < 64 * 16; i += 256) {
        int r = i >> 4, c4 = i & 15;
        uint2 p = *(const uint2*)(A + (row0 + r) * 64 + c4 * 4);
        *(uint2*)(As + r * G1_LD + c4 * 4) = p;
    }
    __syncthreads();

    // ---- phase B: g1 = a1 @ W1, relu(g1+b1) -> G1s f16 ----
    {
        f32x4 acc1[2][4], accl1[2][4];
        #pragma unroll
        for (int t = 0; t < 2; ++t)
            #pragma unroll
            for (int rt = 0; rt < 4; ++rt) {
                acc1[t][rt]  = (f32x4){0.f, 0.f, 0.f, 0.f};
                accl1[t][rt] = (f32x4){0.f, 0.f, 0.f, 0.f};
            }
        #pragma unroll
        for (int kc = 0; kc < 2; ++kc) {
            #pragma unroll
            for (int rt = 0; rt < 4; ++rt) {
                f16x8 a = *(const f16x8*)(As + (rt * 16 + n15) * G1_LD + kc * 32 + quad * 8);
                acc1[0][rt]  = __builtin_amdgcn_mfma_f32_16x16x32_f16(a, w1h[0][kc], acc1[0][rt],  0, 0, 0);
                accl1[0][rt] = __builtin_amdgcn_mfma_f32_16x16x32_f16(a, w1l[0][kc], accl1[0][rt], 0, 0, 0);
                if (nt1 == 2) {
                    acc1[1][rt]  = __builtin_amdgcn_mfma_f32_16x16x32_f16(a, w1h[1][kc], acc1[1][rt],  0, 0, 0);
                    accl1[1][rt] = __builtin_amdgcn_mfma_f32_16x16x32_f16(a, w1l[1][kc], accl1[1][rt], 0, 0, 0);
                }
            }
        }
        #pragma unroll
        for (int t = 0; t < 2; ++t) {
            if (t < nt1) {
                const int col = (wv + 4 * t) * 16 + n15;
                #pragma unroll
                for (int rt = 0; rt < 4; ++rt) {
                    f32x4 c = acc1[t][rt] + accl1[t][rt] * (1.f / 2048.f);
                    #pragma unroll
                    for (int r = 0; r < 4; ++r) {
                        int row = rt * 16 + quad * 4 + r;
                        G1s[row * G2_LD + col] = (_Float16)fmaxf(c[r] + b1c[t], 0.f);
                    }
                }
            }
        }
    }
    __syncthreads();

    // ---- phase C: h2 = bf16(dis * (relu_g1 @ W2)) ----
    {
        f32x4 acc[4], accl[4];
        #pragma unroll
        for (int rt = 0; rt < 4; ++rt) {
            acc[rt]  = (f32x4){0.f, 0.f, 0.f, 0.f};
            accl[rt] = (f32x4){0.f, 0.f, 0.f, 0.f};
        }
        #pragma unroll
        for (int kc = 0; kc < 3; ++kc) {
            #pragma unroll
            for (int rt = 0; rt < 4; ++rt) {
                f16x8 a = *(const f16x8*)(G1s + (rt * 16 + n15) * G2_LD + kc * 32 + quad * 8);
                acc[rt]  = __builtin_amdgcn_mfma_f32_16x16x32_f16(a, w2h[kc], acc[rt],  0, 0, 0);
                accl[rt] = __builtin_amdgcn_mfma_f32_16x16x32_f16(a, w2l[kc], accl[rt], 0, 0, 0);
            }
        }
        const int col = wv * 16 + n15;
        #pragma unroll
        for (int rt = 0; rt < 4; ++rt) {
            f32x4 c = acc[rt] + accl[rt] * (1.f / 2048.f);
            #pragma unroll
            for (int r = 0; r < 4; ++r) {
                int row = rt * 16 + quad * 4 + r;
                float v = c[r] * ds[row];
                h2out[(row0 + row) * 64 + col] = f32_bf16_rtne(v);
            }
        }
    }
}

// ---------------- GCN aggregation: gather over packed CSR (rng int2 ranges) ----------------
template<int C4>
__global__ __launch_bounds__(256) void gcn_gather(const uint2* __restrict__ h, const int2* __restrict__ rng,
                                                  const int2* __restrict__ ent, const float* __restrict__ dis,
                                                  unsigned short* __restrict__ g) {
    unsigned int idx = blockIdx.x * 256 + threadIdx.x;
    unsigned int n = idx / C4, q = idx % C4;
    float4 acc = unp4(h[(size_t)n * C4 + q]);
    int2 r = rng[n];
    int e = r.x;
    for (; e + 8 <= r.y; e += 8) {
        int2 en0 = ent[e],     en1 = ent[e + 1], en2 = ent[e + 2], en3 = ent[e + 3];
        int2 en4 = ent[e + 4], en5 = ent[e + 5], en6 = ent[e + 6], en7 = ent[e + 7];
        uint2 v0 = h[(size_t)en0.x * C4 + q];
        uint2 v1 = h[(size_t)en1.x * C4 + q];
        uint2 v2 = h[(size_t)en2.x * C4 + q];
        uint2 v3 = h[(size_t)en3.x * C4 + q];
        uint2 v4 = h[(size_t)en4.x * C4 + q];
        uint2 v5 = h[(size_t)en5.x * C4 + q];
        uint2 v6 = h[(size_t)en6.x * C4 + q];
        uint2 v7 = h[(size_t)en7.x * C4 + q];
        fma4(acc, __int_as_float(en0.y), unp4(v0));
        fma4(acc, __int_as_float(en1.y), unp4(v1));
        fma4(acc, __int_as_float(en2.y), unp4(v2));
        fma4(acc, __int_as_float(en3.y), unp4(v3));
        fma4(acc, __int_as_float(en4.y), unp4(v4));
        fma4(acc, __int_as_float(en5.y), unp4(v5));
        fma4(acc, __int_as_float(en6.y), unp4(v6));
        fma4(acc, __int_as_float(en7.y), unp4(v7));
    }
    for (; e + 4 <= r.y; e += 4) {
        int2 en0 = ent[e], en1 = ent[e + 1], en2 = ent[e + 2], en3 = ent[e + 3];
        uint2 v0 = h[(size_t)en0.x * C4 + q];
        uint2 v1 = h[(size_t)en1.x * C4 + q];
        uint2 v2 = h[(size_t)en2.x * C4 + q];
        uint2 v3 = h[(size_t)en3.x * C4 + q];
        fma4(acc, __int_as_float(en0.y), unp4(v0));
        fma4(acc, __int_as_float(en1.y), unp4(v1));
        fma4(acc, __int_as_float(en2.y), unp4(v2));
        fma4(acc, __int_as_float(en3.y), unp4(v3));
    }
    for (; e < r.y; ++e) {
        int2 en = ent[e];
        uint2 v = h[(size_t)en.x * C4 + q];
        fma4(acc, __int_as_float(en.y), unp4(v));
    }
    float dn = dis[n];
    acc.x *= dn; acc.y *= dn; acc.z *= dn; acc.w *= dn;
    *(uint2*)(g + (size_t)n * (C4 * 4) + q * 4) = pkh4(acc);
}

// ---------------- fused LSTM: x-path GEMM + recurrence, all MFMA (f16, split planes) ----------------
// v3: 8 waves (512 thr), 2 gate-tiles per wave. Best measured variant (~41us,
// 88 VGPR). Do NOT fuse epilogues in (R12: VGPR 88->120 slowed loop 46->71us).
#define XP_LD 72   // xpack seq-row stride (halves): 4*(n15+quad) bank spread
#define HP_LD2 72  // h plane row stride (halves)
#define GP_LD 258  // gp row stride (floats): store banks 8q+2r+n15 = 2/bank floor

__global__ __launch_bounds__(512, 1) void lstm_kernel(
    const __half* __restrict__ g2, const float* __restrict__ cb2,
    const float* __restrict__ whh, const float* __restrict__ wih,
    const float* __restrict__ bih, const float* __restrict__ bhh,
    float* __restrict__ hlast)
{
    __shared__ __align__(16) _Float16 xpack[32 * 16 * XP_LD];  // 73.7 KB
    __shared__ __align__(16) _Float16 hhi[16 * HP_LD2];        // 2.25 KB
    __shared__ __align__(16) _Float16 hlo[16 * HP_LD2];        // 2.25 KB
    __shared__ float gp[16 * GP_LD];                           // 16.1 KB
    const int tid  = threadIdx.x;       // 0..511
    const int lane = tid & 63;
    const int wv   = tid >> 6;          // wave 0..7
    const int n15  = lane & 15;         // A: seq m / B: gate-in-tile n
    const int quad = lane >> 4;         // k sub-block
    const int ja   = lane;              // activation hidden unit 0..63

    // ---- loop-invariant B-frags for 2 gate tiles: gate = (wv+8*tl)*16+n15 ----
    f16x8 whh_h[2][2], whh_l[2][2], wih_h[2][2], wih_l[2][2];  // [tile][kc]
    #pragma unroll
    for (int tl = 0; tl < 2; ++tl) {
        const int gate = (wv + 8 * tl) * 16 + n15;
        const float* wp = whh + (size_t)gate * 64 + quad * 8;
        const float* xp = wih + (size_t)gate * 64 + quad * 8;
        #pragma unroll
        for (int kc = 0; kc < 2; ++kc) {
            #pragma unroll
            for (int j = 0; j < 8; ++j) {
                float w = wp[kc * 32 + j];
                _Float16 h = (_Float16)w;
                whh_h[tl][kc][j] = h;
                whh_l[tl][kc][j] = (_Float16)((w - (float)h) * 2048.f);
                float v = xp[kc * 32 + j];
                _Float16 g = (_Float16)v;
                wih_h[tl][kc][j] = g;
                wih_l[tl][kc][j] = (_Float16)((v - (float)g) * 2048.f);
            }
        }
    }

    // ---- activation-phase gate biases (b_ih + b_hh), f32 (depend on ja only) ----
    const float bi_i = bih[ja]        + bhh[ja];
    const float bi_f = bih[64 + ja]   + bhh[64 + ja];
    const float bi_g = bih[128 + ja]  + bhh[128 + ja];
    const float bi_o = bih[192 + ja]  + bhh[192 + ja];

    // ---- prologue: stage xr = relu(g2 + conv2_b) into xpack, fully coalesced ----
    {
        const int s0 = blockIdx.x * 16;          // 400 % 16 == 0: block never straddles b_
        const int b_ = s0 / NODESC;
        const int node0 = s0 - b_ * NODESC;
        const int r  = (tid >> 4) & 15;          // seq row (fixed per thread)
        const int c4 = tid & 15;                 // 4-half group within row
        const int t0 = tid >> 8;                 // 0..1; t = t0 + 2*i
        float4 bias4 = *(const float4*)(cb2 + c4 * 4);
        _Float16* dst = xpack + r * XP_LD + c4 * 4;
        const __half* src = g2 + ((size_t)(b_ * TT + t0) * NODESC + node0 + r) * 64 + c4 * 4;
        #pragma unroll
        for (int i = 0; i < 16; ++i) {
            uint2 p = *(const uint2*)(src + (size_t)i * 2 * NODESC * 64);
            float4 v = uph4(p);
            v.x = fmaxf(v.x + bias4.x, 0.f);
            v.y = fmaxf(v.y + bias4.y, 0.f);
            v.z = fmaxf(v.z + bias4.z, 0.f);
            v.w = fmaxf(v.w + bias4.w, 0.f);
            *(uint2*)(dst + (size_t)(t0 + i * 2) * (16 * XP_LD)) = pkh4(v);
        }
    }

    // ---- init h = 0 ----
    for (int i = tid; i < 16 * HP_LD2; i += 512) { hhi[i] = (_Float16)0.f; hlo[i] = (_Float16)0.f; }
    float cA_reg = 0.f, hA = 0.f;   // state for (qa = wv, ja)
    float cB_reg = 0.f, hB = 0.f;   // state for (qa = wv+8, ja)
    __syncthreads();

    const int xbase = n15 * XP_LD + quad * 8;    // halves, 16B-aligned
    const int hbase = n15 * HP_LD2 + quad * 8;

    for (int t = 0; t < TT; ++t) {
        // ---- dot phase: 6 A-frag reads shared by 2 tiles, 20 MFMAs, 6 chains ----
        f32x4 cmA  = {0.f,0.f,0.f,0.f}, clA0 = {0.f,0.f,0.f,0.f}, clA1 = {0.f,0.f,0.f,0.f};
        f32x4 cmB  = {0.f,0.f,0.f,0.f}, clB0 = {0.f,0.f,0.f,0.f}, clB1 = {0.f,0.f,0.f,0.f};
        const _Float16* xrow = xpack + (size_t)t * (16 * XP_LD);
        {
            f16x8 ax0 = *(const f16x8*)(xrow + xbase);
            f16x8 ah0 = *(const f16x8*)(hhi + hbase);
            f16x8 al0 = *(const f16x8*)(hlo + hbase);
            f16x8 ax1 = *(const f16x8*)(xrow + xbase + 32);
            f16x8 ah1 = *(const f16x8*)(hhi + hbase + 32);
            f16x8 al1 = *(const f16x8*)(hlo + hbase + 32);
            cmA  = __builtin_amdgcn_mfma_f32_16x16x32_f16(ax0, wih_h[0][0], cmA,  0, 0, 0);
            cmB  = __builtin_amdgcn_mfma_f32_16x16x32_f16(ax0, wih_h[1][0], cmB,  0, 0, 0);
            clA0 = __builtin_amdgcn_mfma_f32_16x16x32_f16(ax0, wih_l[0][0], clA0, 0, 0, 0);
            clB0 = __builtin_amdgcn_mfma_f32_16x16x32_f16(ax0, wih_l[1][0], clB0, 0, 0, 0);
            clA1 = __builtin_amdgcn_mfma_f32_16x16x32_f16(ax1, wih_l[0][1], clA1, 0, 0, 0);
            clB1 = __builtin_amdgcn_mfma_f32_16x16x32_f16(ax1, wih_l[1][1], clB1, 0, 0, 0);
            cmA  = __builtin_amdgcn_mfma_f32_16x16x32_f16(ah0, whh_h[0][0], cmA,  0, 0, 0);
            cmB  = __builtin_amdgcn_mfma_f32_16x16x32_f16(ah0, whh_h[1][0], cmB,  0, 0, 0);
            clA0 = __builtin_amdgcn_mfma_f32_16x16x32_f16(al0, whh_h[0][0], clA0, 0, 0, 0);
            clB0 = __builtin_amdgcn_mfma_f32_16x16x32_f16(al0, whh_h[1][0], clB0, 0, 0, 0);
            clA1 = __builtin_amdgcn_mfma_f32_16x16x32_f16(al1, whh_h[0][1], clA1, 0, 0, 0);
            clB1 = __builtin_amdgcn_mfma_f32_16x16x32_f16(al1, whh_h[1][1], clB1, 0, 0, 0);
            cmA  = __builtin_amdgcn_mfma_f32_16x16x32_f16(ax1, wih_h[0][1], cmA,  0, 0, 0);
            cmB  = __builtin_amdgcn_mfma_f32_16x16x32_f16(ax1, wih_h[1][1], cmB,  0, 0, 0);
            clA0 = __builtin_amdgcn_mfma_f32_16x16x32_f16(ah0, whh_l[0][0], clA0, 0, 0, 0);
            clB0 = __builtin_amdgcn_mfma_f32_16x16x32_f16(ah0, whh_l[1][0], clB0, 0, 0, 0);
            clA1 = __builtin_amdgcn_mfma_f32_16x16x32_f16(ah1, whh_l[0][1], clA1, 0, 0, 0);
            clB1 = __builtin_amdgcn_mfma_f32_16x16x32_f16(ah1, whh_l[1][1], clB1, 0, 0, 0);
            cmA  = __builtin_amdgcn_mfma_f32_16x16x32_f16(ah1, whh_h[0][1], cmA,  0, 0, 0);
            cmB  = __builtin_amdgcn_mfma_f32_16x16x32_f16(ah1, whh_h[1][1], cmB,  0, 0, 0);
        }
        f32x4 cA = cmA + (clA0 + clA1) * (1.f / 2048.f);
        f32x4 cB = cmB + (clB0 + clB1) * (1.f / 2048.f);
        // C: lane holds seqs m = quad*4+r; columns wv*16+n15 and (wv+8)*16+n15
        #pragma unroll
        for (int r = 0; r < 4; ++r) {
            gp[(quad * 4 + r) * GP_LD + wv * 16 + n15]       = cA[r];
            gp[(quad * 4 + r) * GP_LD + (wv + 8) * 16 + n15] = cB[r];
        }
        __syncthreads();

        // ---- activation phase: thread handles (wv, ja) and (wv+8, ja) ----
        {
            const int qa = wv;
            float gi = gp[qa * GP_LD + ja]        + bi_i;
            float gf = gp[qa * GP_LD + 64 + ja]   + bi_f;
            float gg = gp[qa * GP_LD + 128 + ja]  + bi_g;
            float go = gp[qa * GP_LD + 192 + ja]  + bi_o;
            cA_reg = sigm_f(gf) * cA_reg + sigm_f(gi) * tanh_f(gg);
            hA = sigm_f(go) * tanh_f(cA_reg);
            _Float16 hh = (_Float16)hA;
            hhi[qa * HP_LD2 + ja] = hh;
            hlo[qa * HP_LD2 + ja] = (_Float16)((hA - (float)hh) * 2048.f);
        }
        {
            const int qa = wv + 8;
            float gi = gp[qa * GP_LD + ja]        + bi_i;
            float gf = gp[qa * GP_LD + 64 + ja]   + bi_f;
            float gg = gp[qa * GP_LD + 128 + ja]  + bi_g;
            float go = gp[qa * GP_LD + 192 + ja]  + bi_o;
            cB_reg = sigm_f(gf) * cB_reg + sigm_f(gi) * tanh_f(gg);
            hB = sigm_f(go) * tanh_f(cB_reg);
            _Float16 hh = (_Float16)hB;
            hhi[qa * HP_LD2 + ja] = hh;
            hlo[qa * HP_LD2 + ja] = (_Float16)((hB - (float)hh) * 2048.f);
        }
        __syncthreads();
    }
    hlast[((size_t)blockIdx.x * 16 + wv) * 64 + ja]     = hA;
    hlast[((size_t)blockIdx.x * 16 + wv + 8) * 64 + ja] = hB;
}

// ---------------- FC head + softmax ----------------
__global__ __launch_bounds__(128) void head_kernel(const float* __restrict__ hl,
                                                   const float* __restrict__ w1, const float* __restrict__ b1,
                                                   const float* __restrict__ w2, const float* __restrict__ b2,
                                                   float* __restrict__ out) {
    __shared__ float hrow[64];
    __shared__ float a1[128];
    __shared__ float lg[3];
    int s = blockIdx.x, tid = threadIdx.x;
    if (tid < 64) hrow[tid] = hl[(size_t)s * 64 + tid];
    __syncthreads();
    {
        const float4* wr = (const float4*)(w1 + (size_t)tid * 64);
        const float4* hq = (const float4*)hrow;
        float4 acc = make_float4(0.f, 0.f, 0.f, 0.f);
        #pragma unroll
        for (int k = 0; k < 16; ++k) {
            float4 wv = wr[k]; float4 hv = hq[k];
            acc.x = fmaf(wv.x, hv.x, acc.x); acc.y = fmaf(wv.y, hv.y, acc.y);
            acc.z = fmaf(wv.z, hv.z, acc.z); acc.w = fmaf(wv.w, hv.w, acc.w);
        }
        a1[tid] = fmaxf((acc.x + acc.y) + (acc.z + acc.w) + b1[tid], 0.f);
    }
    __syncthreads();
    if (tid < 3) {
        const float4* wr = (const float4*)(w2 + (size_t)tid * 128);
        const float4* aq = (const float4*)a1;
        float4 acc = make_float4(0.f, 0.f, 0.f, 0.f);
        #pragma unroll
        for (int k = 0; k < 32; ++k) {
            float4 wv = wr[k]; float4 av = aq[k];
            acc.x = fmaf(wv.x, av.x, acc.x); acc.y = fmaf(wv.y, av.y, acc.y);
            acc.z = fmaf(wv.z, av.z, acc.z); acc.w = fmaf(wv.w, av.w, acc.w);
        }
        lg[tid] = (acc.x + acc.y) + (acc.z + acc.w) + b2[tid];
    }
    __syncthreads();
    if (tid == 0) {
        float m = fmaxf(lg[0], fmaxf(lg[1], lg[2]));
        float e0 = __expf(lg[0] - m), e1 = __expf(lg[1] - m), e2 = __expf(lg[2] - m);
        float inv = 1.f / (e0 + e1 + e2);
        out[(size_t)s * 3 + 0] = e0 * inv;
        out[(size_t)s * 3 + 1] = e1 * inv;
        out[(size_t)s * 3 + 2] = e2 * inv;
    }
}

extern "C" void kernel_launch(void* const* d_in, const int* in_sizes, int n_in,
                              void* d_out, int out_size, void* d_ws, size_t ws_size,
                              hipStream_t stream) {
    (void)in_sizes; (void)n_in; (void)out_size; (void)ws_size;
    const float* x        = (const float*)d_in[0];
    const float* ea       = (const float*)d_in[1];
    const float* conv1_w  = (const float*)d_in[2];
    const float* conv1_b  = (const float*)d_in[3];
    const float* conv2_w  = (const float*)d_in[4];
    const float* conv2_b  = (const float*)d_in[5];
    const float* w_ih     = (const float*)d_in[6];
    const float* w_hh     = (const float*)d_in[7];
    const float* b_ih     = (const float*)d_in[8];
    const float* b_hh     = (const float*)d_in[9];
    const float* fc1_w    = (const float*)d_in[10];
    const float* fc1_b    = (const float*)d_in[11];
    const float* fc2_w    = (const float*)d_in[12];
    const float* fc2_b    = (const float*)d_in[13];
    const int*   ei       = (const int*)d_in[14];
    float* out = (float*)d_out;

    float* W    = (float*)d_ws;
    int2*  ent  = (int2*)(W + OFF_ENT);
    unsigned short* a1h = (unsigned short*)(W + OFF_A1);   // fp16 a1 rows
    int2*  ent2 = (int2*)(W + OFF_ENT2);
    uint2* xnd  = (uint2*)(W + OFF_ENT2);  // bf16 rows; reuses dead csr staging
    float* h2   = W + OFF_H2;              // bf16 rows; overwrites dead xnd (sequentially safe)
    unsigned short* g2h = (unsigned short*)(W + OFF_G2);   // fp16 rows
    int*   gcur = (int*)(W + OFF_GCUR);
    float* dis  = W + OFF_DIS;
    int2*  rng  = (int2*)(W + OFF_RNG);
    float* hl   = W + OFF_HL;
    float* st   = W + OFF_ST;

    // init (zeroes gcur + st)
    init_zero<<<26, 256, 0, stream>>>(gcur, st);

    // merged: edge partition (latency-bound) + col sums (BW-bound) co-scheduled
    part_cols<<<NPART + NCOLB, PTHR, 0, stream>>>(ei, ea, gcur, ent2, x, st);
    finalize_stats<<<1, 64, 0, stream>>>(st);

    // per-bucket counting sort -> packed CSR + dis
    bucket_csr<<<NBUK, 256, 0, stream>>>(ent2, gcur, ent, rng, dis);

    // pre-scaled bf16 node features: xnd = bf16(dis * normalize(x))
    xnd_kernel<<<NN * 16 / 256, 256, 0, stream>>>(x, st, dis, xnd);

    // GCN layer 1 aggregation (full parallelism): a1 = S·xnd (fp16 out)
    gcn_gather<16><<<NN * 16 / 256, 256, 0, stream>>>(xnd, rng, ent, dis, a1h);

    // fused GEMM 1+2: h2 = bf16(dis*(relu(a1@W1 + b1)@W2)) — saves g1 round-trip
    fused_gemm12<<<NN / 64, 256, 0, stream>>>(a1h, conv1_w, conv1_b, conv2_w, dis,
                                              (unsigned short*)h2);

    // GCN layer 2 aggregation: g2 = S·h2 (fp16 out)
    gcn_gather<16><<<NN * 16 / 256, 256, 0, stream>>>((const uint2*)h2, rng, ent, dis, g2h);

    // fused LSTM v3: x-path GEMM + recurrence, all MFMA f16
    lstm_kernel<<<SS / 16, 512, 0, stream>>>((const __half*)g2h, conv2_b, w_hh, w_ih,
                                             b_ih, b_hh, hl);

    // FC head + softmax
    head_kernel<<<SS, 128, 0, stream>>>(hl, fc1_w, fc1_b, fc2_w, fc2_b, out);
}

// Round 16
// 310.168 us; speedup vs baseline: 1.1276x; 1.0380x over previous
//
#include <hip/hip_runtime.h>
#include <hip/hip_bf16.h>
#include <hip/hip_fp16.h>

#define NN 102400      // B*T*NODES
#define DD 64
#define EE 1638400
#define L1C 96
#define L2C 64
#define TT 32
#define NODESC 400
#define BB 8
#define SS 3200        // B*NODES
#define G4 256         // 4*D

#define NBUK 400       // coarse buckets (node >> 8), NN = 400*256 exactly
#define BCAP 5120      // slots per bucket (mean 4096, sd 64 -> +16 sigma)
#define PCHUNK 4096    // 400 blocks x 512 thr: all part blocks co-resident, half the gcur atomics
#define NPART (EE / PCHUNK)   // 400
#define PTHR 512
#define EPT (PCHUNK / PTHR)   // 8 edges per thread
#define EPB (BCAP / 256)      // 20 entries per thread in bucket_csr
#define NCOLB 512             // col-sum blocks appended to the part grid

// ---------------- workspace layout (floats) ----------------
#define OFF_ENT  ((size_t)0)          // NBUK*BCAP int2 = 4,096,000 floats
#define OFF_A1   ((size_t)4096000)    // NN*64 fp16 a1 rows
#define OFF_ENT2 ((size_t)26214400)   // csr staging; then xnd bf16; then h2 bf16
#define OFF_H2   ((size_t)26214400)   // NN*64 bf16 (overwrites dead xnd)
#define OFF_G2   ((size_t)32768000)   // NN*64 fp16
#define OFF_GCUR ((size_t)39321600)   // 400 cursors padded x16 ints = 6400
#define OFF_DIS  ((size_t)39328000)   // NN -> ends 39,430,400
#define OFF_RNG  ((size_t)39430400)   // NN int2 -> ends 39,635,200
#define OFF_HL   ((size_t)39635200)   // SS*64 -> ends 39,840,000
#define OFF_ST   ((size_t)39840000)   // 256 -> ends 39,840,256

typedef __attribute__((ext_vector_type(8))) _Float16 f16x8;  // 8 f16 in 4 VGPRs
typedef __attribute__((ext_vector_type(4))) float f32x4;

__device__ __forceinline__ void fma4(float4& a, float s, const float4& w) {
    a.x = fmaf(s, w.x, a.x); a.y = fmaf(s, w.y, a.y);
    a.z = fmaf(s, w.z, a.z); a.w = fmaf(s, w.w, a.w);
}
__device__ __forceinline__ float rcp_f(float x) { return __builtin_amdgcn_rcpf(x); }
__device__ __forceinline__ float sigm_f(float x) {
    x = fminf(fmaxf(x, -30.f), 30.f);
    return rcp_f(1.f + __expf(-x));
}
__device__ __forceinline__ float tanh_f(float x) {
    x = fminf(fmaxf(x, -15.f), 15.f);
    float e = __expf(2.f * x);
    return (e - 1.f) * rcp_f(e + 1.f);
}
__device__ __forceinline__ unsigned short f32_bf16_rtne(float f) {
    unsigned int u = __float_as_uint(f);
    unsigned int r = u + 0x7fffu + ((u >> 16) & 1u);
    return (unsigned short)(r >> 16);
}
__device__ __forceinline__ float bf16_f32(unsigned short h) {
    return __uint_as_float(((unsigned int)h) << 16);
}
// bf16 x4 pack/unpack (gather tables)
__device__ __forceinline__ float4 unp4(uint2 p) {
    float4 v;
    v.x = __uint_as_float(p.x << 16);
    v.y = __uint_as_float(p.x & 0xffff0000u);
    v.z = __uint_as_float(p.y << 16);
    v.w = __uint_as_float(p.y & 0xffff0000u);
    return v;
}
__device__ __forceinline__ uint2 pk4(float4 v) {
    unsigned int u0 = ((unsigned int)f32_bf16_rtne(v.y) << 16) | f32_bf16_rtne(v.x);
    unsigned int u1 = ((unsigned int)f32_bf16_rtne(v.w) << 16) | f32_bf16_rtne(v.z);
    return make_uint2(u0, u1);
}
// fp16 x4 pack/unpack (GEMM intermediates)
__device__ __forceinline__ uint2 pkh4(float4 v) {
    __half2 h0 = __floats2half2_rn(v.x, v.y);
    __half2 h1 = __floats2half2_rn(v.z, v.w);
    uint2 r;
    r.x = *(unsigned int*)&h0;
    r.y = *(unsigned int*)&h1;
    return r;
}
__device__ __forceinline__ float4 uph4(uint2 p) {
    __half2 h0 = *(__half2*)&p.x;
    __half2 h1 = *(__half2*)&p.y;
    float2 f0 = __half22float2(h0), f1 = __half22float2(h1);
    return make_float4(f0.x, f0.y, f1.x, f1.y);
}

// ---------------- init: zero bucket cursors + stats ----------------
__global__ void init_zero(int* gcur, float* st) {
    int idx = blockIdx.x * 256 + threadIdx.x;
    if (idx < NBUK * 16) gcur[idx] = 0;
    if (blockIdx.x == 0 && threadIdx.x < 128) st[threadIdx.x] = 0.f;
}

// ---------------- xnd = bf16( dis[n] * normalize(x[n]) ) ----------------
__global__ __launch_bounds__(256) void xnd_kernel(const float* __restrict__ x, const float* __restrict__ st,
                                                  const float* __restrict__ dis, uint2* __restrict__ xnd) {
    size_t i = (size_t)blockIdx.x * 256 + threadIdx.x;   // float4 index
    int n = (int)(i >> 4), q = (int)(i & 15);
    float4 v = ((const float4*)x)[i];
    float4 mean4 = ((const float4*)(st + 128))[q];
    float4 istd4 = ((const float4*)(st + 192))[q];
    float dn = dis[n];
    v.x = (v.x - mean4.x) * istd4.x * dn;
    v.y = (v.y - mean4.y) * istd4.y * dn;
    v.z = (v.z - mean4.z) * istd4.z * dn;
    v.w = (v.w - mean4.w) * istd4.w * dn;
    xnd[i] = pk4(v);
}

// ---------------- merged pass 1 + col_sums (heterogeneous grid) ----------------
// PCHUNK=4096: 400 part blocks (all co-resident at 2 blocks/CU), half the
// gcur atomic traffic, 24 in-flight loads/thread. blockIdx < NPART ->
// partition; else col-sums (grid-strided). Bodies byte-identical otherwise.
__global__ __launch_bounds__(PTHR) void part_cols(const int* __restrict__ ei, const float* __restrict__ ea,
                                                  int* __restrict__ gcur, int2* __restrict__ ent2,
                                                  const float* __restrict__ x, float* __restrict__ st) {
    __shared__ int lhist[NBUK];        // counts, then reused as scatter cursors
    __shared__ int lofs[NBUK];         // block-local exclusive offsets
    __shared__ int lbase[NBUK];        // global within-bucket base (from gcur)
    __shared__ int scn[PTHR];          // scan workspace
    __shared__ int2 stage[PCHUNK];     // 32 KB bucket-sorted staging
    __shared__ int  gdst[PCHUNK];      // 16 KB absolute destinations (-1 = drop)
    __shared__ float ls[128];          // col-sums reduction
    const int tid = threadIdx.x;

    if (blockIdx.x >= NPART) {
        // ---- col_sums path ----
        const int cb = blockIdx.x - NPART;
        int c = tid & 63;
        size_t i = (size_t)cb * PTHR + tid;
        size_t stride = (size_t)NCOLB * PTHR;
        float s = 0.f, q = 0.f;
        for (size_t e = i; e < (size_t)NN * 64; e += stride) {
            float v = x[e]; s += v; q = fmaf(v, v, q);
        }
        if (tid < 128) ls[tid] = 0.f;
        __syncthreads();
        atomicAdd(&ls[c], s); atomicAdd(&ls[64 + c], q);
        __syncthreads();
        if (tid < 128) atomicAdd(&st[tid], ls[tid]);
        return;
    }

    // ---- partition path ----
    const int e0 = blockIdx.x * PCHUNK;
    for (int i = tid; i < NBUK; i += PTHR) lhist[i] = 0;
    __syncthreads();
    int   dv[EPT]; int sv[EPT]; float wvv[EPT];
    #pragma unroll
    for (int i = 0; i < EPT; ++i) {
        int e = e0 + i * PTHR + tid;
        dv[i]  = ei[EE + e];
        sv[i]  = ei[e];
        wvv[i] = fabsf(ea[2 * (size_t)e]);
        atomicAdd(&lhist[dv[i] >> 8], 1);
    }
    __syncthreads();
    // exclusive prefix over bucket counts (Hillis-Steele over PTHR lanes)
    scn[tid] = (tid < NBUK) ? lhist[tid] : 0;
    __syncthreads();
    for (int d = 1; d < PTHR; d <<= 1) {
        int t = (tid >= d) ? scn[tid - d] : 0;
        __syncthreads();
        scn[tid] += t;
        __syncthreads();
    }
    if (tid < NBUK) {
        lofs[tid]  = scn[tid] - lhist[tid];                  // exclusive
        lbase[tid] = atomicAdd(&gcur[tid * 16], lhist[tid]); // reserve global run
        lhist[tid] = 0;                                      // reuse as cursor
    }
    __syncthreads();
    // scatter into bucket-sorted LDS staging + precompute global destination
    #pragma unroll
    for (int i = 0; i < EPT; ++i) {
        int d = dv[i];
        int b = d >> 8;
        int li = atomicAdd(&lhist[b], 1);
        int pos = lofs[b] + li;
        stage[pos] = make_int2(sv[i] | ((d & 255) << 24), __float_as_int(wvv[i]));
        int gp_ = lbase[b] + li;
        gdst[pos] = (gp_ < BCAP) ? (b * BCAP + gp_) : -1;
    }
    __syncthreads();
    // write out: consecutive lanes cover consecutive addresses within segments
    for (int i = tid; i < PCHUNK; i += PTHR) {
        int g = gdst[i];
        if (g >= 0) ent2[g] = stage[i];
    }
}

// ---------------- pass 2: per-bucket counting sort in LDS + rng + dis ----------------
// v4: register-cached entries; coalesced write-out; block 0 also runs
// finalize_stats (st sums complete once part_cols retired) — saves a launch.
__global__ __launch_bounds__(256) void bucket_csr(const int2* __restrict__ ent2, const int* __restrict__ gcur,
                                                  int2* __restrict__ ent, int2* __restrict__ rng,
                                                  float* __restrict__ dis, float* __restrict__ st) {
    __shared__ int nhist[256];
    __shared__ int scn[256];
    __shared__ float wsum[256];
    __shared__ int pcur[256];
    __shared__ int2 sorted[BCAP];   // 40 KB
    const int tid = threadIdx.x;
    const int b = blockIdx.x;
    if (b == 0 && tid < 64) {       // fused finalize_stats
        float s = st[tid], q = st[64 + tid];
        float mean = s / (float)NN;
        float var = (q - s * s / (float)NN) / (float)(NN - 1);
        st[128 + tid] = mean;
        st[192 + tid] = rsqrtf(fmaxf(var, 1e-20f));
    }
    const int base = b * BCAP;
    int cnt = gcur[b * 16];
    if (cnt > BCAP) cnt = BCAP;
    nhist[tid] = 0;
    wsum[tid] = 0.f;
    __syncthreads();
    int   meta[EPB]; float wv_[EPB];
    #pragma unroll
    for (int i = 0; i < EPB; ++i) {
        int e = tid + i * 256;
        if (e < cnt) {
            int2 en = ent2[base + e];
            meta[i] = en.x;
            wv_[i]  = __int_as_float(en.y);
            int dl = ((unsigned)en.x) >> 24;
            atomicAdd(&nhist[dl], 1);
            atomicAdd(&wsum[dl], wv_[i]);
        } else {
            meta[i] = 0; wv_[i] = 0.f;
        }
    }
    __syncthreads();
    int c = nhist[tid];
    scn[tid] = c;
    __syncthreads();
    for (int d = 1; d < 256; d <<= 1) {
        int t = (tid >= d) ? scn[tid - d] : 0;
        __syncthreads();
        scn[tid] += t;
        __syncthreads();
    }
    int ps = scn[tid] - c;                       // exclusive prefix within bucket
    rng[b * 256 + tid] = make_int2(base + ps, base + ps + c);
    dis[b * 256 + tid] = rsqrtf(1.f + wsum[tid]); // self-loop weight 1 folded in
    pcur[tid] = ps;
    __syncthreads();
    #pragma unroll
    for (int i = 0; i < EPB; ++i) {
        int e = tid + i * 256;
        if (e < cnt) {
            int dl = ((unsigned)meta[i]) >> 24;
            int local = atomicAdd(&pcur[dl], 1);
            sorted[local] = make_int2(meta[i] & 0xFFFFFF, __float_as_int(wv_[i]));
        }
    }
    __syncthreads();
    // coalesced write-out
    for (int e = tid; e < cnt; e += 256)
        ent[base + e] = sorted[e];
}

// ---------------- fused MFMA GEMM 1+2: h2 = bf16(dis*(relu(a1@W1 + b1)@W2)) ----------------
#define G1_LD 72
#define G2_LD 104
__global__ __launch_bounds__(256) void fused_gemm12(
    const unsigned short* __restrict__ A, const float* __restrict__ W1,
    const float* __restrict__ b1v, const float* __restrict__ W2,
    const float* __restrict__ dscale, unsigned short* __restrict__ h2out)
{
    __shared__ __align__(16) _Float16 As[64 * G1_LD];    // a1 rows f16 (9.2 KB)
    __shared__ __align__(16) _Float16 G1s[64 * G2_LD];   // relu(g1+b1) f16 (13.3 KB)
    __shared__ float ds[64];
    const int tid  = threadIdx.x;
    const int lane = tid & 63;
    const int wv   = tid >> 6;          // wave 0..3
    const int n15  = lane & 15;
    const int quad = lane >> 4;
    const size_t row0 = (size_t)blockIdx.x * 64;

    if (tid < 64) ds[tid] = dscale[row0 + tid];

    // ---- W1 frags: ctiles {wv, wv+4 if wv<2} covering 0..5; hi + lo*2048 f16 ----
    const int nt1 = (wv < 2) ? 2 : 1;
    f16x8 w1h[2][2], w1l[2][2];
    float b1c[2] = {0.f, 0.f};
    #pragma unroll
    for (int t = 0; t < 2; ++t) {
        if (t < nt1) {
            const int col = (wv + 4 * t) * 16 + n15;
            b1c[t] = b1v[col];
            #pragma unroll
            for (int kc = 0; kc < 2; ++kc) {
                #pragma unroll
                for (int j = 0; j < 8; ++j) {
                    float w = W1[(size_t)(kc * 32 + quad * 8 + j) * 96 + col];
                    _Float16 h = (_Float16)w;
                    w1h[t][kc][j] = h;
                    w1l[t][kc][j] = (_Float16)((w - (float)h) * 2048.f);
                }
            }
        }
    }
    // ---- W2 frags: ctile wv, col = wv*16+n15, 3 k-chunks ----
    f16x8 w2h[3], w2l[3];
    {
        const int col = wv * 16 + n15;
        #pragma unroll
        for (int kc = 0; kc < 3; ++kc) {
            #pragma unroll
            for (int j = 0; j < 8; ++j) {
                float w = W2[(size_t)(kc * 32 + quad * 8 + j) * 64 + col];
                _Float16 h = (_Float16)w;
                w2h[kc][j] = h;
                w2l[kc][j] = (_Float16)((w - (float)h) * 2048.f);
            }
        }
    }

    // ---- stage a1 rows (already fp16): coalesced uint2 copy ----
    for (int i = tid; i < 64 * 16; i += 256) {
        int r = i >> 4, c4 = i & 15;
        uint2 p = *(const uint2*)(A + (row0 + r) * 64 + c4 * 4);
        *(uint2*)(As + r * G1_LD + c4 * 4) = p;
    }
    __syncthreads();

    // ---- phase B: g1 = a1 @ W1, relu(g1+b1) -> G1s f16 ----
    {
        f32x4 acc1[2][4], accl1[2][4];
        #pragma unroll
        for (int t = 0; t < 2; ++t)
            #pragma unroll
            for (int rt = 0; rt < 4; ++rt) {
                acc1[t][rt]  = (f32x4){0.f, 0.f, 0.f, 0.f};
                accl1[t][rt] = (f32x4){0.f, 0.f, 0.f, 0.f};
            }
        #pragma unroll
        for (int kc = 0; kc < 2; ++kc) {
            #pragma unroll
            for (int rt = 0; rt < 4; ++rt) {
                f16x8 a = *(const f16x8*)(As + (rt * 16 + n15) * G1_LD + kc * 32 + quad * 8);
                acc1[0][rt]  = __builtin_amdgcn_mfma_f32_16x16x32_f16(a, w1h[0][kc], acc1[0][rt],  0, 0, 0);
                accl1[0][rt] = __builtin_amdgcn_mfma_f32_16x16x32_f16(a, w1l[0][kc], accl1[0][rt], 0, 0, 0);
                if (nt1 == 2) {
                    acc1[1][rt]  = __builtin_amdgcn_mfma_f32_16x16x32_f16(a, w1h[1][kc], acc1[1][rt],  0, 0, 0);
                    accl1[1][rt] = __builtin_amdgcn_mfma_f32_16x16x32_f16(a, w1l[1][kc], accl1[1][rt], 0, 0, 0);
                }
            }
        }
        #pragma unroll
        for (int t = 0; t < 2; ++t) {
            if (t < nt1) {
                const int col = (wv + 4 * t) * 16 + n15;
                #pragma unroll
                for (int rt = 0; rt < 4; ++rt) {
                    f32x4 c = acc1[t][rt] + accl1[t][rt] * (1.f / 2048.f);
                    #pragma unroll
                    for (int r = 0; r < 4; ++r) {
                        int row = rt * 16 + quad * 4 + r;
                        G1s[row * G2_LD + col] = (_Float16)fmaxf(c[r] + b1c[t], 0.f);
                    }
                }
            }
        }
    }
    __syncthreads();

    // ---- phase C: h2 = bf16(dis * (relu_g1 @ W2)) ----
    {
        f32x4 acc[4], accl[4];
        #pragma unroll
        for (int rt = 0; rt < 4; ++rt) {
            acc[rt]  = (f32x4){0.f, 0.f, 0.f, 0.f};
            accl[rt] = (f32x4){0.f, 0.f, 0.f, 0.f};
        }
        #pragma unroll
        for (int kc = 0; kc < 3; ++kc) {
            #pragma unroll
            for (int rt = 0; rt < 4; ++rt) {
                f16x8 a = *(const f16x8*)(G1s + (rt * 16 + n15) * G2_LD + kc * 32 + quad * 8);
                acc[rt]  = __builtin_amdgcn_mfma_f32_16x16x32_f16(a, w2h[kc], acc[rt],  0, 0, 0);
                accl[rt] = __builtin_amdgcn_mfma_f32_16x16x32_f16(a, w2l[kc], accl[rt], 0, 0, 0);
            }
        }
        const int col = wv * 16 + n15;
        #pragma unroll
        for (int rt = 0; rt < 4; ++rt) {
            f32x4 c = acc[rt] + accl[rt] * (1.f / 2048.f);
            #pragma unroll
            for (int r = 0; r < 4; ++r) {
                int row = rt * 16 + quad * 4 + r;
                float v = c[r] * ds[row];
                h2out[(row0 + row) * 64 + col] = f32_bf16_rtne(v);
            }
        }
    }
}

// ---------------- GCN aggregation: gather over packed CSR (rng int2 ranges) ----------------
template<int C4>
__global__ __launch_bounds__(256) void gcn_gather(const uint2* __restrict__ h, const int2* __restrict__ rng,
                                                  const int2* __restrict__ ent, const float* __restrict__ dis,
                                                  unsigned short* __restrict__ g) {
    unsigned int idx = blockIdx.x * 256 + threadIdx.x;
    unsigned int n = idx / C4, q = idx % C4;
    float4 acc = unp4(h[(size_t)n * C4 + q]);
    int2 r = rng[n];
    int e = r.x;
    for (; e + 8 <= r.y; e += 8) {
        int2 en0 = ent[e],     en1 = ent[e + 1], en2 = ent[e + 2], en3 = ent[e + 3];
        int2 en4 = ent[e + 4], en5 = ent[e + 5], en6 = ent[e + 6], en7 = ent[e + 7];
        uint2 v0 = h[(size_t)en0.x * C4 + q];
        uint2 v1 = h[(size_t)en1.x * C4 + q];
        uint2 v2 = h[(size_t)en2.x * C4 + q];
        uint2 v3 = h[(size_t)en3.x * C4 + q];
        uint2 v4 = h[(size_t)en4.x * C4 + q];
        uint2 v5 = h[(size_t)en5.x * C4 + q];
        uint2 v6 = h[(size_t)en6.x * C4 + q];
        uint2 v7 = h[(size_t)en7.x * C4 + q];
        fma4(acc, __int_as_float(en0.y), unp4(v0));
        fma4(acc, __int_as_float(en1.y), unp4(v1));
        fma4(acc, __int_as_float(en2.y), unp4(v2));
        fma4(acc, __int_as_float(en3.y), unp4(v3));
        fma4(acc, __int_as_float(en4.y), unp4(v4));
        fma4(acc, __int_as_float(en5.y), unp4(v5));
        fma4(acc, __int_as_float(en6.y), unp4(v6));
        fma4(acc, __int_as_float(en7.y), unp4(v7));
    }
    for (; e + 4 <= r.y; e += 4) {
        int2 en0 = ent[e], en1 = ent[e + 1], en2 = ent[e + 2], en3 = ent[e + 3];
        uint2 v0 = h[(size_t)en0.x * C4 + q];
        uint2 v1 = h[(size_t)en1.x * C4 + q];
        uint2 v2 = h[(size_t)en2.x * C4 + q];
        uint2 v3 = h[(size_t)en3.x * C4 + q];
        fma4(acc, __int_as_float(en0.y), unp4(v0));
        fma4(acc, __int_as_float(en1.y), unp4(v1));
        fma4(acc, __int_as_float(en2.y), unp4(v2));
        fma4(acc, __int_as_float(en3.y), unp4(v3));
    }
    for (; e < r.y; ++e) {
        int2 en = ent[e];
        uint2 v = h[(size_t)en.x * C4 + q];
        fma4(acc, __int_as_float(en.y), unp4(v));
    }
    float dn = dis[n];
    acc.x *= dn; acc.y *= dn; acc.z *= dn; acc.w *= dn;
    *(uint2*)(g + (size_t)n * (C4 * 4) + q * 4) = pkh4(acc);
}

// ---------------- fused LSTM: x-path GEMM + recurrence, all MFMA (f16, split planes) ----------------
// v3: 8 waves (512 thr), 2 gate-tiles per wave. Best measured variant (~41us,
// 88 VGPR). Do NOT fuse epilogues in (R12: VGPR 88->120 slowed loop 46->71us).
#define XP_LD 72   // xpack seq-row stride (halves): 4*(n15+quad) bank spread
#define HP_LD2 72  // h plane row stride (halves)
#define GP_LD 258  // gp row stride (floats): store banks 8q+2r+n15 = 2/bank floor

__global__ __launch_bounds__(512, 1) void lstm_kernel(
    const __half* __restrict__ g2, const float* __restrict__ cb2,
    const float* __restrict__ whh, const float* __restrict__ wih,
    const float* __restrict__ bih, const float* __restrict__ bhh,
    float* __restrict__ hlast)
{
    __shared__ __align__(16) _Float16 xpack[32 * 16 * XP_LD];  // 73.7 KB
    __shared__ __align__(16) _Float16 hhi[16 * HP_LD2];        // 2.25 KB
    __shared__ __align__(16) _Float16 hlo[16 * HP_LD2];        // 2.25 KB
    __shared__ float gp[16 * GP_LD];                           // 16.1 KB
    const int tid  = threadIdx.x;       // 0..511
    const int lane = tid & 63;
    const int wv   = tid >> 6;          // wave 0..7
    const int n15  = lane & 15;         // A: seq m / B: gate-in-tile n
    const int quad = lane >> 4;         // k sub-block
    const int ja   = lane;              // activation hidden unit 0..63

    // ---- loop-invariant B-frags for 2 gate tiles: gate = (wv+8*tl)*16+n15 ----
    f16x8 whh_h[2][2], whh_l[2][2], wih_h[2][2], wih_l[2][2];  // [tile][kc]
    #pragma unroll
    for (int tl = 0; tl < 2; ++tl) {
        const int gate = (wv + 8 * tl) * 16 + n15;
        const float* wp = whh + (size_t)gate * 64 + quad * 8;
        const float* xp = wih + (size_t)gate * 64 + quad * 8;
        #pragma unroll
        for (int kc = 0; kc < 2; ++kc) {
            #pragma unroll
            for (int j = 0; j < 8; ++j) {
                float w = wp[kc * 32 + j];
                _Float16 h = (_Float16)w;
                whh_h[tl][kc][j] = h;
                whh_l[tl][kc][j] = (_Float16)((w - (float)h) * 2048.f);
                float v = xp[kc * 32 + j];
                _Float16 g = (_Float16)v;
                wih_h[tl][kc][j] = g;
                wih_l[tl][kc][j] = (_Float16)((v - (float)g) * 2048.f);
            }
        }
    }

    // ---- activation-phase gate biases (b_ih + b_hh), f32 (depend on ja only) ----
    const float bi_i = bih[ja]        + bhh[ja];
    const float bi_f = bih[64 + ja]   + bhh[64 + ja];
    const float bi_g = bih[128 + ja]  + bhh[128 + ja];
    const float bi_o = bih[192 + ja]  + bhh[192 + ja];

    // ---- prologue: stage xr = relu(g2 + conv2_b) into xpack, fully coalesced ----
    {
        const int s0 = blockIdx.x * 16;          // 400 % 16 == 0: block never straddles b_
        const int b_ = s0 / NODESC;
        const int node0 = s0 - b_ * NODESC;
        const int r  = (tid >> 4) & 15;          // seq row (fixed per thread)
        const int c4 = tid & 15;                 // 4-half group within row
        const int t0 = tid >> 8;                 // 0..1; t = t0 + 2*i
        float4 bias4 = *(const float4*)(cb2 + c4 * 4);
        _Float16* dst = xpack + r * XP_LD + c4 * 4;
        const __half* src = g2 + ((size_t)(b_ * TT + t0) * NODESC + node0 + r) * 64 + c4 * 4;
        #pragma unroll
        for (int i = 0; i < 16; ++i) {
            uint2 p = *(const uint2*)(src + (size_t)i * 2 * NODESC * 64);
            float4 v = uph4(p);
            v.x = fmaxf(v.x + bias4.x, 0.f);
            v.y = fmaxf(v.y + bias4.y, 0.f);
            v.z = fmaxf(v.z + bias4.z, 0.f);
            v.w = fmaxf(v.w + bias4.w, 0.f);
            *(uint2*)(dst + (size_t)(t0 + i * 2) * (16 * XP_LD)) = pkh4(v);
        }
    }

    // ---- init h = 0 ----
    for (int i = tid; i < 16 * HP_LD2; i += 512) { hhi[i] = (_Float16)0.f; hlo[i] = (_Float16)0.f; }
    float cA_reg = 0.f, hA = 0.f;   // state for (qa = wv, ja)
    float cB_reg = 0.f, hB = 0.f;   // state for (qa = wv+8, ja)
    __syncthreads();

    const int xbase = n15 * XP_LD + quad * 8;    // halves, 16B-aligned
    const int hbase = n15 * HP_LD2 + quad * 8;

    for (int t = 0; t < TT; ++t) {
        // ---- dot phase: 6 A-frag reads shared by 2 tiles, 20 MFMAs, 6 chains ----
        f32x4 cmA  = {0.f,0.f,0.f,0.f}, clA0 = {0.f,0.f,0.f,0.f}, clA1 = {0.f,0.f,0.f,0.f};
        f32x4 cmB  = {0.f,0.f,0.f,0.f}, clB0 = {0.f,0.f,0.f,0.f}, clB1 = {0.f,0.f,0.f,0.f};
        const _Float16* xrow = xpack + (size_t)t * (16 * XP_LD);
        {
            f16x8 ax0 = *(const f16x8*)(xrow + xbase);
            f16x8 ah0 = *(const f16x8*)(hhi + hbase);
            f16x8 al0 = *(const f16x8*)(hlo + hbase);
            f16x8 ax1 = *(const f16x8*)(xrow + xbase + 32);
            f16x8 ah1 = *(const f16x8*)(hhi + hbase + 32);
            f16x8 al1 = *(const f16x8*)(hlo + hbase + 32);
            cmA  = __builtin_amdgcn_mfma_f32_16x16x32_f16(ax0, wih_h[0][0], cmA,  0, 0, 0);
            cmB  = __builtin_amdgcn_mfma_f32_16x16x32_f16(ax0, wih_h[1][0], cmB,  0, 0, 0);
            clA0 = __builtin_amdgcn_mfma_f32_16x16x32_f16(ax0, wih_l[0][0], clA0, 0, 0, 0);
            clB0 = __builtin_amdgcn_mfma_f32_16x16x32_f16(ax0, wih_l[1][0], clB0, 0, 0, 0);
            clA1 = __builtin_amdgcn_mfma_f32_16x16x32_f16(ax1, wih_l[0][1], clA1, 0, 0, 0);
            clB1 = __builtin_amdgcn_mfma_f32_16x16x32_f16(ax1, wih_l[1][1], clB1, 0, 0, 0);
            cmA  = __builtin_amdgcn_mfma_f32_16x16x32_f16(ah0, whh_h[0][0], cmA,  0, 0, 0);
            cmB  = __builtin_amdgcn_mfma_f32_16x16x32_f16(ah0, whh_h[1][0], cmB,  0, 0, 0);
            clA0 = __builtin_amdgcn_mfma_f32_16x16x32_f16(al0, whh_h[0][0], clA0, 0, 0, 0);
            clB0 = __builtin_amdgcn_mfma_f32_16x16x32_f16(al0, whh_h[1][0], clB0, 0, 0, 0);
            clA1 = __builtin_amdgcn_mfma_f32_16x16x32_f16(al1, whh_h[0][1], clA1, 0, 0, 0);
            clB1 = __builtin_amdgcn_mfma_f32_16x16x32_f16(al1, whh_h[1][1], clB1, 0, 0, 0);
            cmA  = __builtin_amdgcn_mfma_f32_16x16x32_f16(ax1, wih_h[0][1], cmA,  0, 0, 0);
            cmB  = __builtin_amdgcn_mfma_f32_16x16x32_f16(ax1, wih_h[1][1], cmB,  0, 0, 0);
            clA0 = __builtin_amdgcn_mfma_f32_16x16x32_f16(ah0, whh_l[0][0], clA0, 0, 0, 0);
            clB0 = __builtin_amdgcn_mfma_f32_16x16x32_f16(ah0, whh_l[1][0], clB0, 0, 0, 0);
            clA1 = __builtin_amdgcn_mfma_f32_16x16x32_f16(ah1, whh_l[0][1], clA1, 0, 0, 0);
            clB1 = __builtin_amdgcn_mfma_f32_16x16x32_f16(ah1, whh_l[1][1], clB1, 0, 0, 0);
            cmA  = __builtin_amdgcn_mfma_f32_16x16x32_f16(ah1, whh_h[0][1], cmA,  0, 0, 0);
            cmB  = __builtin_amdgcn_mfma_f32_16x16x32_f16(ah1, whh_h[1][1], cmB,  0, 0, 0);
        }
        f32x4 cA = cmA + (clA0 + clA1) * (1.f / 2048.f);
        f32x4 cB = cmB + (clB0 + clB1) * (1.f / 2048.f);
        // C: lane holds seqs m = quad*4+r; columns wv*16+n15 and (wv+8)*16+n15
        #pragma unroll
        for (int r = 0; r < 4; ++r) {
            gp[(quad * 4 + r) * GP_LD + wv * 16 + n15]       = cA[r];
            gp[(quad * 4 + r) * GP_LD + (wv + 8) * 16 + n15] = cB[r];
        }
        __syncthreads();

        // ---- activation phase: thread handles (wv, ja) and (wv+8, ja) ----
        {
            const int qa = wv;
            float gi = gp[qa * GP_LD + ja]        + bi_i;
            float gf = gp[qa * GP_LD + 64 + ja]   + bi_f;
            float gg = gp[qa * GP_LD + 128 + ja]  + bi_g;
            float go = gp[qa * GP_LD + 192 + ja]  + bi_o;
            cA_reg = sigm_f(gf) * cA_reg + sigm_f(gi) * tanh_f(gg);
            hA = sigm_f(go) * tanh_f(cA_reg);
            _Float16 hh = (_Float16)hA;
            hhi[qa * HP_LD2 + ja] = hh;
            hlo[qa * HP_LD2 + ja] = (_Float16)((hA - (float)hh) * 2048.f);
        }
        {
            const int qa = wv + 8;
            float gi = gp[qa * GP_LD + ja]        + bi_i;
            float gf = gp[qa * GP_LD + 64 + ja]   + bi_f;
            float gg = gp[qa * GP_LD + 128 + ja]  + bi_g;
            float go = gp[qa * GP_LD + 192 + ja]  + bi_o;
            cB_reg = sigm_f(gf) * cB_reg + sigm_f(gi) * tanh_f(gg);
            hB = sigm_f(go) * tanh_f(cB_reg);
            _Float16 hh = (_Float16)hB;
            hhi[qa * HP_LD2 + ja] = hh;
            hlo[qa * HP_LD2 + ja] = (_Float16)((hB - (float)hh) * 2048.f);
        }
        __syncthreads();
    }
    hlast[((size_t)blockIdx.x * 16 + wv) * 64 + ja]     = hA;
    hlast[((size_t)blockIdx.x * 16 + wv + 8) * 64 + ja] = hB;
}

// ---------------- FC head + softmax ----------------
__global__ __launch_bounds__(128) void head_kernel(const float* __restrict__ hl,
                                                   const float* __restrict__ w1, const float* __restrict__ b1,
                                                   const float* __restrict__ w2, const float* __restrict__ b2,
                                                   float* __restrict__ out) {
    __shared__ float hrow[64];
    __shared__ float a1[128];
    __shared__ float lg[3];
    int s = blockIdx.x, tid = threadIdx.x;
    if (tid < 64) hrow[tid] = hl[(size_t)s * 64 + tid];
    __syncthreads();
    {
        const float4* wr = (const float4*)(w1 + (size_t)tid * 64);
        const float4* hq = (const float4*)hrow;
        float4 acc = make_float4(0.f, 0.f, 0.f, 0.f);
        #pragma unroll
        for (int k = 0; k < 16; ++k) {
            float4 wv = wr[k]; float4 hv = hq[k];
            acc.x = fmaf(wv.x, hv.x, acc.x); acc.y = fmaf(wv.y, hv.y, acc.y);
            acc.z = fmaf(wv.z, hv.z, acc.z); acc.w = fmaf(wv.w, hv.w, acc.w);
        }
        a1[tid] = fmaxf((acc.x + acc.y) + (acc.z + acc.w) + b1[tid], 0.f);
    }
    __syncthreads();
    if (tid < 3) {
        const float4* wr = (const float4*)(w2 + (size_t)tid * 128);
        const float4* aq = (const float4*)a1;
        float4 acc = make_float4(0.f, 0.f, 0.f, 0.f);
        #pragma unroll
        for (int k = 0; k < 32; ++k) {
            float4 wv = wr[k]; float4 av = aq[k];
            acc.x = fmaf(wv.x, av.x, acc.x); acc.y = fmaf(wv.y, av.y, acc.y);
            acc.z = fmaf(wv.z, av.z, acc.z); acc.w = fmaf(wv.w, av.w, acc.w);
        }
        lg[tid] = (acc.x + acc.y) + (acc.z + acc.w) + b2[tid];
    }
    __syncthreads();
    if (tid == 0) {
        float m = fmaxf(lg[0], fmaxf(lg[1], lg[2]));
        float e0 = __expf(lg[0] - m), e1 = __expf(lg[1] - m), e2 = __expf(lg[2] - m);
        float inv = 1.f / (e0 + e1 + e2);
        out[(size_t)s * 3 + 0] = e0 * inv;
        out[(size_t)s * 3 + 1] = e1 * inv;
        out[(size_t)s * 3 + 2] = e2 * inv;
    }
}

extern "C" void kernel_launch(void* const* d_in, const int* in_sizes, int n_in,
                              void* d_out, int out_size, void* d_ws, size_t ws_size,
                              hipStream_t stream) {
    (void)in_sizes; (void)n_in; (void)out_size; (void)ws_size;
    const float* x        = (const float*)d_in[0];
    const float* ea       = (const float*)d_in[1];
    const float* conv1_w  = (const float*)d_in[2];
    const float* conv1_b  = (const float*)d_in[3];
    const float* conv2_w  = (const float*)d_in[4];
    const float* conv2_b  = (const float*)d_in[5];
    const float* w_ih     = (const float*)d_in[6];
    const float* w_hh     = (const float*)d_in[7];
    const float* b_ih     = (const float*)d_in[8];
    const float* b_hh     = (const float*)d_in[9];
    const float* fc1_w    = (const float*)d_in[10];
    const float* fc1_b    = (const float*)d_in[11];
    const float* fc2_w    = (const float*)d_in[12];
    const float* fc2_b    = (const float*)d_in[13];
    const int*   ei       = (const int*)d_in[14];
    float* out = (float*)d_out;

    float* W    = (float*)d_ws;
    int2*  ent  = (int2*)(W + OFF_ENT);
    unsigned short* a1h = (unsigned short*)(W + OFF_A1);   // fp16 a1 rows
    int2*  ent2 = (int2*)(W + OFF_ENT2);
    uint2* xnd  = (uint2*)(W + OFF_ENT2);  // bf16 rows; reuses dead csr staging
    float* h2   = W + OFF_H2;              // bf16 rows; overwrites dead xnd (sequentially safe)
    unsigned short* g2h = (unsigned short*)(W + OFF_G2);   // fp16 rows
    int*   gcur = (int*)(W + OFF_GCUR);
    float* dis  = W + OFF_DIS;
    int2*  rng  = (int2*)(W + OFF_RNG);
    float* hl   = W + OFF_HL;
    float* st   = W + OFF_ST;

    // init (zeroes gcur + st)
    init_zero<<<26, 256, 0, stream>>>(gcur, st);

    // merged: edge partition (latency-bound) + col sums (BW-bound) co-scheduled
    part_cols<<<NPART + NCOLB, PTHR, 0, stream>>>(ei, ea, gcur, ent2, x, st);

    // per-bucket counting sort -> packed CSR + dis (block 0 also finalizes stats)
    bucket_csr<<<NBUK, 256, 0, stream>>>(ent2, gcur, ent, rng, dis, st);

    // pre-scaled bf16 node features: xnd = bf16(dis * normalize(x))
    xnd_kernel<<<NN * 16 / 256, 256, 0, stream>>>(x, st, dis, xnd);

    // GCN layer 1 aggregation (full parallelism): a1 = S·xnd (fp16 out)
    gcn_gather<16><<<NN * 16 / 256, 256, 0, stream>>>(xnd, rng, ent, dis, a1h);

    // fused GEMM 1+2: h2 = bf16(dis*(relu(a1@W1 + b1)@W2)) — saves g1 round-trip
    fused_gemm12<<<NN / 64, 256, 0, stream>>>(a1h, conv1_w, conv1_b, conv2_w, dis,
                                              (unsigned short*)h2);

    // GCN layer 2 aggregation: g2 = S·h2 (fp16 out)
    gcn_gather<16><<<NN * 16 / 256, 256, 0, stream>>>((const uint2*)h2, rng, ent, dis, g2h);

    // fused LSTM v3: x-path GEMM + recurrence, all MFMA f16
    lstm_kernel<<<SS / 16, 512, 0, stream>>>((const __half*)g2h, conv2_b, w_hh, w_ih,
                                             b_ih, b_hh, hl);

    // FC head + softmax
    head_kernel<<<SS, 128, 0, stream>>>(hl, fc1_w, fc1_b, fc2_w, fc2_b, out);
}